// Round 10
// baseline (377.607 us; speedup 1.0000x reference)
//
#include <hip/hip_runtime.h>
#include <math.h>

#define IDIM 32
#define KNN 16
#define NPTS 8192
#define NBATCH 16
#define PPB 16                      // points per block
#define CLAMPV 1.9f
#define TWO_OVER_PI 0.63661977236758134f

typedef __attribute__((ext_vector_type(8))) short bf16x8;   // 8 bf16 = 4 VGPR (MFMA A/B)
typedef __attribute__((ext_vector_type(4))) float f32x4;    // MFMA C/D
typedef __attribute__((ext_vector_type(2))) short s16x2;

// Compiler-friendly bf16 pack: scalar __bf16 casts fuse to v_cvt_pk_bf16_f32.
__device__ __forceinline__ unsigned pk2(float a, float b) {
    union { __bf16 h[2]; unsigned u; } r;
    r.h[0] = (__bf16)a; r.h[1] = (__bf16)b;
    return r.u;
}
__device__ __forceinline__ unsigned short f2bf(float f) {
    union { __bf16 h; unsigned short u; } r; r.h = (__bf16)f; return r.u;
}

// ReLU on a packed bf16 pair: IEEE sign-magnitude => per-half smax(x,0) == relu.
__device__ __forceinline__ unsigned relu2(unsigned p) {
    s16x2 v; __builtin_memcpy(&v, &p, 4);
    s16x2 z = {0, 0};
    s16x2 m = __builtin_elementwise_max(v, z);
    unsigned r; __builtin_memcpy(&r, &m, 4);
    return r;
}

// Raw ds_swizzle (BitMode XOR) — 1 DS op, no lane-index VALU math.
template<int PAT>
__device__ __forceinline__ float swzf(float v) {
    return __int_as_float(__builtin_amdgcn_ds_swizzle(__float_as_int(v), PAT));
}
__device__ __forceinline__ float red_max16(float o) {
    o = fmaxf(o, swzf<0x041F>(o));   // xor 1
    o = fmaxf(o, swzf<0x081F>(o));   // xor 2
    o = fmaxf(o, swzf<0x101F>(o));   // xor 4
    o = fmaxf(o, swzf<0x201F>(o));   // xor 8
    return o;
}
__device__ __forceinline__ float red_sum16(float o) {
    o += swzf<0x041F>(o); o += swzf<0x081F>(o);
    o += swzf<0x101F>(o); o += swzf<0x201F>(o);
    return o;
}

// ---------------------------------------------------------------------------
// Precompute MFMA A-fragments (bf16) for all 4 networks into ws.
// mfma_f32_16x16x32_bf16 A-layout: lane l holds A[row=l&15][k=(l>>4)*8+j], j=0..7.
// Frag f element order in ws: f*512 + lane*8 + j.
// Frag table per net u (fb = u*14):
//   fb+c        (c=0..3)        : L1  A_c[row][k] = W1f[k][16c+row]
//   fb+4+2c+kc  (c=0..3,kc=0..1): L2  A[row][k]   = W2[kc*32+k][16c+row]
//   fb+12+kc    (kc=0..1)       : L3  A[row][k]   = W3[kc*32+k][row]
// W1f rows: k<16 -> WA[k]=W1[k]-W1[32+k]; k>=16 -> WB[k-16]=W1[k]+W1[k+16]
// ---------------------------------------------------------------------------
__global__ void prep_frags(const float* __restrict__ W1, const float* __restrict__ W2,
                           const float* __restrict__ W3, unsigned short* __restrict__ wsb) {
    int e = blockIdx.x * 256 + threadIdx.x;       // 0 .. 56*512-1
    if (e >= 56 * 512) return;
    int f = e >> 9, idx = e & 511;
    int lane = idx >> 3, j = idx & 7;
    int row = lane & 15, g = lane >> 4;
    int k = g * 8 + j;                            // 0..31
    int u = f / 14, t = f % 14;
    float val;
    if (t < 4) {
        int h = 16 * t + row;
        const float* w = W1 + u * 3072;           // (48,64) row-major
        val = (k < 16) ? (w[k * 64 + h] - w[(32 + k) * 64 + h])
                       : (w[k * 64 + h] + w[(k + 16) * 64 + h]);
    } else if (t < 12) {
        int c = (t - 4) >> 1, kc = (t - 4) & 1;
        val = W2[u * 4096 + (kc * 32 + k) * 64 + 16 * c + row];
    } else {
        int kc = t - 12;
        val = W3[u * 1024 + (kc * 32 + k) * 16 + row];
    }
    wsb[e] = f2bf(val);
}

// ---------------------------------------------------------------------------
// z[b,n,d] = x[b,n,31-d]*exp(logs[d]) + bias[d]; init log_det[b].
// Optionally also writes z1 (dims 0..15) pre-packed to bf16 (MFMA-ready) so
// the gather kernel loads 16B/lane with zero pack work.
// ---------------------------------------------------------------------------
__global__ void affine_rev(const float* __restrict__ x, const float* __restrict__ logs,
                           const float* __restrict__ bias, float* __restrict__ out,
                           unsigned short* __restrict__ z1bf) {
    __shared__ float ssc[IDIM], sbi[IDIM];
    int tid = threadIdx.x;
    if (tid < IDIM) { ssc[tid] = expf(logs[tid]); sbi[tid] = bias[tid]; }
    __syncthreads();
    size_t p = (size_t)blockIdx.x * blockDim.x + tid;
    if (p < (size_t)NBATCH * NPTS) {
        const float4* xr = (const float4*)(x + p * IDIM);
        float xv[IDIM];
#pragma unroll
        for (int q = 0; q < 8; ++q) {
            float4 v = xr[q];
            xv[q * 4 + 0] = v.x; xv[q * 4 + 1] = v.y; xv[q * 4 + 2] = v.z; xv[q * 4 + 3] = v.w;
        }
        float zv[IDIM];
#pragma unroll
        for (int d = 0; d < IDIM; ++d) zv[d] = xv[31 - d] * ssc[d] + sbi[d];
        float4* zr = (float4*)(out + p * IDIM);
#pragma unroll
        for (int q = 0; q < 8; ++q) {
            float4 v;
            v.x = zv[q * 4 + 0]; v.y = zv[q * 4 + 1];
            v.z = zv[q * 4 + 2]; v.w = zv[q * 4 + 3];
            zr[q] = v;
        }
        if (z1bf) {
            union { uint4 q[2]; unsigned w[8]; } pk;
#pragma unroll
            for (int d = 0; d < 8; ++d) pk.w[d] = pk2(zv[2 * d], zv[2 * d + 1]);
            uint4* zp = (uint4*)(z1bf + p * 16);
            zp[0] = pk.q[0]; zp[1] = pk.q[1];
        }
    }
    if (blockIdx.x == 0 && tid < NBATCH) {
        float sl = 0.f;
#pragma unroll
        for (int d = 0; d < IDIM; ++d) sl += logs[d];
        out[(size_t)NBATCH * NPTS * IDIM + tid] = sl * (float)NPTS;
    }
}

// ---------------------------------------------------------------------------
// MFMA conv kernel, 2-pt ILP + feature prefetch.
// r10: ZBF=1 -> gathers load pre-packed bf16 z1 (16B/lane, no pk2);
// LDS staging stride 18 u64 (144B) so fragment reads are single ds_read_b128
// (even offsets => 16B aligned); write-side 2-way bank alias is free (m136).
// ---------------------------------------------------------------------------
template<int ZBF>
__global__ __launch_bounds__(256, 3)
void knn_mfma(const int* __restrict__ knn, const unsigned short* __restrict__ wsb,
              const unsigned short* __restrict__ z1b,
              const float* __restrict__ B1, const float* __restrict__ B2,
              const float* __restrict__ B3, float* __restrict__ out) {
    __shared__ __align__(16) unsigned long long hq[4 * 2 * 288];  // [wave][ptA/B][16 x 18]
    __shared__ float stg[PPB * 4 * 16];                   // [pt][net][dim]
    __shared__ float ldsum[16];
    __shared__ int   sidx[PPB * KNN];                     // 256 knn indices for this block

    const int tid = threadIdx.x;
    const int u = tid >> 6, lane = tid & 63;
    const int g = lane >> 4, x = lane & 15;
    const int pbase = blockIdx.x * PPB;
    const int bb = pbase >> 13;                           // batch (PPB divides 8192)

    // --- stage knn indices (one coalesced load per thread) ---
    sidx[tid] = knn[(size_t)pbase * KNN + tid];

    // --- weight fragments (persist across the point loop) ---
    bf16x8 a1[4], a2k0[4], a2k1[4], a30, a31;
    const int fb = u * 14;
#pragma unroll
    for (int c = 0; c < 4; ++c)
        a1[c] = *(const bf16x8*)(wsb + (size_t)(fb + c) * 512 + lane * 8);
#pragma unroll
    for (int c = 0; c < 4; ++c) {
        a2k0[c] = *(const bf16x8*)(wsb + (size_t)(fb + 4 + 2 * c + 0) * 512 + lane * 8);
        a2k1[c] = *(const bf16x8*)(wsb + (size_t)(fb + 4 + 2 * c + 1) * 512 + lane * 8);
    }
    a30 = *(const bf16x8*)(wsb + (size_t)(fb + 12) * 512 + lane * 8);
    a31 = *(const bf16x8*)(wsb + (size_t)(fb + 13) * 512 + lane * 8);

    // --- biases as persistent MFMA C-operands: lane owns rows 16c+4g..+3 ---
    f32x4 b1v[4], b2v[4], b3v;
#pragma unroll
    for (int c = 0; c < 4; ++c) {
        b1v[c] = *(const f32x4*)(B1 + u * 64 + 16 * c + 4 * g);
        b2v[c] = *(const f32x4*)(B2 + u * 64 + 16 * c + 4 * g);
    }
    b3v = *(const f32x4*)(B3 + u * 16 + 4 * g);

    // --- LDS staging offsets in u64 units; stride 18; swizzle even ---
    const int baseA = (u * 2 + 0) * 288;
    const int baseB = (u * 2 + 1) * 288;
    const int swq = (x & 7) << 1;
    int woq[4];
#pragma unroll
    for (int c = 0; c < 4; ++c) woq[c] = x * 18 + ((4 * c + g) ^ swq);
    const int rq0 = x * 18 + ((2 * g) ^ swq);             // even -> 16B aligned
    const int rq1 = x * 18 + ((8 + 2 * g) ^ swq);         // even -> 16B aligned

    const int off = (g & 1) * 8;
    const float* zb = out + (size_t)bb * NPTS * IDIM;     // batch base (f32 path)
    const unsigned short* z1p = z1b + (size_t)bb * NPTS * 16;  // bf16 path
    const int baseRow = pbase & (NPTS - 1);               // local row of pbase

    __syncthreads();                                      // sidx visible

    // --- prologue: features for pair 0 ---
    union fu { bf16x8 v; uint4 q; unsigned w[4]; };
    uint4 pAq, pBq, nAq, nBq;
    float4 pA0, pA1, pB0, pB1, nA0, nA1, nB0, nB1;
    {
        int iA0 = sidx[x], iB0 = sidx[16 + x];
        int rA = (g < 2) ? baseRow : iA0;
        int rB = (g < 2) ? (baseRow + 1) : iB0;
        if constexpr (ZBF) {
            pAq = *(const uint4*)(z1p + (size_t)rA * 16 + off);
            pBq = *(const uint4*)(z1p + (size_t)rB * 16 + off);
        } else {
            const float* rpA = zb + (size_t)rA * IDIM;
            pA0 = *(const float4*)(rpA + off); pA1 = *(const float4*)(rpA + off + 4);
            const float* rpB = zb + (size_t)rB * IDIM;
            pB0 = *(const float4*)(rpB + off); pB1 = *(const float4*)(rpB + off + 4);
        }
    }

#pragma unroll 2
    for (int pp = 0; pp < PPB / 2; ++pp) {
        // prefetch next pair's features (indices from LDS, just-in-time)
        if (pp < PPB / 2 - 1) {
            int iA1 = sidx[(2 * pp + 2) * 16 + x];
            int iB1 = sidx[(2 * pp + 3) * 16 + x];
            int rA = (g < 2) ? (baseRow + 2 * pp + 2) : iA1;
            int rB = (g < 2) ? (baseRow + 2 * pp + 3) : iB1;
            if constexpr (ZBF) {
                nAq = *(const uint4*)(z1p + (size_t)rA * 16 + off);
                nBq = *(const uint4*)(z1p + (size_t)rB * 16 + off);
            } else {
                const float* rpA = zb + (size_t)rA * IDIM;
                nA0 = *(const float4*)(rpA + off); nA1 = *(const float4*)(rpA + off + 4);
                const float* rpB = zb + (size_t)rB * IDIM;
                nB0 = *(const float4*)(rpB + off); nB1 = *(const float4*)(rpB + off + 4);
            }
        }

        // features as MFMA B-fragments
        fu efA, efB;
        if constexpr (ZBF) {
            efA.q = pAq; efB.q = pBq;
        } else {
            efA.w[0] = pk2(pA0.x, pA0.y); efA.w[1] = pk2(pA0.z, pA0.w);
            efA.w[2] = pk2(pA1.x, pA1.y); efA.w[3] = pk2(pA1.z, pA1.w);
            efB.w[0] = pk2(pB0.x, pB0.y); efB.w[1] = pk2(pB0.z, pB0.w);
            efB.w[2] = pk2(pB1.x, pB1.y); efB.w[3] = pk2(pB1.z, pB1.w);
        }

        // ---- L1 (bias in C) ----
        f32x4 aA[4], aB[4];
        __builtin_amdgcn_s_setprio(1);
#pragma unroll
        for (int c = 0; c < 4; ++c)
            aA[c] = __builtin_amdgcn_mfma_f32_16x16x32_bf16(a1[c], efA.v, b1v[c], 0, 0, 0);
#pragma unroll
        for (int c = 0; c < 4; ++c)
            aB[c] = __builtin_amdgcn_mfma_f32_16x16x32_bf16(a1[c], efB.v, b1v[c], 0, 0, 0);
        __builtin_amdgcn_s_setprio(0);
#pragma unroll
        for (int c = 0; c < 4; ++c) {
            union { unsigned w[2]; unsigned long long q; } qa;
            qa.w[0] = relu2(pk2(aA[c][0], aA[c][1]));
            qa.w[1] = relu2(pk2(aA[c][2], aA[c][3]));
            hq[baseA + woq[c]] = qa.q;
        }
#pragma unroll
        for (int c = 0; c < 4; ++c) {
            union { unsigned w[2]; unsigned long long q; } qb;
            qb.w[0] = relu2(pk2(aB[c][0], aB[c][1]));
            qb.w[1] = relu2(pk2(aB[c][2], aB[c][3]));
            hq[baseB + woq[c]] = qb.q;
        }

        // ---- read h1 (ds_read_b128 each), L2 (bias in C) ----
        fu h0A, h1A, h0B, h1B;
        h0A.q = *(const uint4*)&hq[baseA + rq0];
        h1A.q = *(const uint4*)&hq[baseA + rq1];
        h0B.q = *(const uint4*)&hq[baseB + rq0];
        h1B.q = *(const uint4*)&hq[baseB + rq1];
        f32x4 cA[4], cB[4];
        __builtin_amdgcn_s_setprio(1);
#pragma unroll
        for (int c = 0; c < 4; ++c) {
            cA[c] = __builtin_amdgcn_mfma_f32_16x16x32_bf16(a2k0[c], h0A.v, b2v[c], 0, 0, 0);
            cB[c] = __builtin_amdgcn_mfma_f32_16x16x32_bf16(a2k0[c], h0B.v, b2v[c], 0, 0, 0);
        }
#pragma unroll
        for (int c = 0; c < 4; ++c) {
            cA[c] = __builtin_amdgcn_mfma_f32_16x16x32_bf16(a2k1[c], h1A.v, cA[c], 0, 0, 0);
            cB[c] = __builtin_amdgcn_mfma_f32_16x16x32_bf16(a2k1[c], h1B.v, cB[c], 0, 0, 0);
        }
        __builtin_amdgcn_s_setprio(0);
#pragma unroll
        for (int c = 0; c < 4; ++c) {
            union { unsigned w[2]; unsigned long long q; } qa;
            qa.w[0] = relu2(pk2(cA[c][0], cA[c][1]));
            qa.w[1] = relu2(pk2(cA[c][2], cA[c][3]));
            hq[baseA + woq[c]] = qa.q;
        }
#pragma unroll
        for (int c = 0; c < 4; ++c) {
            union { unsigned w[2]; unsigned long long q; } qb;
            qb.w[0] = relu2(pk2(cB[c][0], cB[c][1]));
            qb.w[1] = relu2(pk2(cB[c][2], cB[c][3]));
            hq[baseB + woq[c]] = qb.q;
        }

        // ---- read h2 (ds_read_b128 each), L3 (bias in C) ----
        fu g0A, g1A, g0B, g1B;
        g0A.q = *(const uint4*)&hq[baseA + rq0];
        g1A.q = *(const uint4*)&hq[baseA + rq1];
        g0B.q = *(const uint4*)&hq[baseB + rq0];
        g1B.q = *(const uint4*)&hq[baseB + rq1];
        f32x4 oA, oB;
        __builtin_amdgcn_s_setprio(1);
        oA = __builtin_amdgcn_mfma_f32_16x16x32_bf16(a30, g0A.v, b3v, 0, 0, 0);
        oB = __builtin_amdgcn_mfma_f32_16x16x32_bf16(a30, g0B.v, b3v, 0, 0, 0);
        oA = __builtin_amdgcn_mfma_f32_16x16x32_bf16(a31, g1A.v, oA, 0, 0, 0);
        oB = __builtin_amdgcn_mfma_f32_16x16x32_bf16(a31, g1B.v, oB, 0, 0, 0);
        __builtin_amdgcn_s_setprio(0);

        // max over neighbors: raw ds_swizzle XOR tree
        float oA0 = red_max16(oA[0]), oA1 = red_max16(oA[1]);
        float oA2 = red_max16(oA[2]), oA3 = red_max16(oA[3]);
        float oB0 = red_max16(oB[0]), oB1 = red_max16(oB[1]);
        float oB2 = red_max16(oB[2]), oB3 = red_max16(oB[3]);

        if (x == 0) {
            *(float4*)&stg[((2 * pp + 0) * 4 + u) * 16 + 4 * g] = make_float4(oA0, oA1, oA2, oA3);
            *(float4*)&stg[((2 * pp + 1) * 4 + u) * 16 + 4 * g] = make_float4(oB0, oB1, oB2, oB3);
        }

        // rotate prefetched features
        if constexpr (ZBF) { pAq = nAq; pBq = nBq; }
        else { pA0 = nA0; pA1 = nA1; pB0 = nB0; pB1 = nB1; }
    }
    __syncthreads();

    // --- epilogue: z2 update + log_det (one atomic per block) ---
    {
        const int pu = u * 4 + g;                  // 0..15
        const int prow = pbase + pu;
        const size_t zoff = (size_t)prow * IDIM + 16 + x;
        float z2v = out[zoff];
        float s1 = stg[(pu * 4 + 0) * 16 + x];
        float t1 = stg[(pu * 4 + 1) * 16 + x];
        float s2 = stg[(pu * 4 + 2) * 16 + x];
        float t2 = stg[(pu * 4 + 3) * 16 + x];
        float sc1 = CLAMPV * TWO_OVER_PI * atanf(s1 * (1.0f / CLAMPV));
        float sc2 = CLAMPV * TWO_OVER_PI * atanf(s2 * (1.0f / CLAMPV));
        z2v = z2v * expf(sc1) + t1;
        z2v = z2v * expf(sc2) + t2;
        out[zoff] = z2v;
        float ss = red_sum16(sc1 + sc2);
        if (x == 0) ldsum[pu] = ss;
    }
    __syncthreads();
    if (tid == 0) {
        float tot = 0.f;
#pragma unroll
        for (int i = 0; i < 16; ++i) tot += ldsum[i];
        atomicAdd(out + (size_t)NBATCH * NPTS * IDIM + bb, tot);
    }
}

extern "C" void kernel_launch(void* const* d_in, const int* in_sizes, int n_in,
                              void* d_out, int out_size, void* d_ws, size_t ws_size,
                              hipStream_t stream) {
    const float* x    = (const float*)d_in[0];
    const int*   knn  = (const int*)d_in[1];
    const float* logs = (const float*)d_in[2];
    const float* bias = (const float*)d_in[3];
    const float* W1   = (const float*)d_in[4];
    const float* b1   = (const float*)d_in[5];
    const float* W2   = (const float*)d_in[6];
    const float* b2   = (const float*)d_in[7];
    const float* W3   = (const float*)d_in[8];
    const float* b3   = (const float*)d_in[9];
    float* out = (float*)d_out;
    unsigned short* wsb = (unsigned short*)d_ws;   // frags: 56*512 shorts = 57344 B
    const size_t need = 56 * 512 * 2 + (size_t)NBATCH * NPTS * 16 * 2;  // frags + z1bf
    const bool zbf = ws_size >= need;
    unsigned short* z1bf = zbf ? (wsb + 56 * 512) : nullptr;

    hipLaunchKernelGGL(prep_frags, dim3(112), dim3(256), 0, stream, W1, W2, W3, wsb);
    hipLaunchKernelGGL(affine_rev, dim3(512), dim3(256), 0, stream, x, logs, bias, out, z1bf);
    if (zbf)
        hipLaunchKernelGGL((knn_mfma<1>), dim3((NBATCH * NPTS) / PPB), dim3(256), 0, stream,
                           knn, wsb, z1bf, b1, b2, b3, out);
    else
        hipLaunchKernelGGL((knn_mfma<0>), dim3((NBATCH * NPTS) / PPB), dim3(256), 0, stream,
                           knn, wsb, wsb, b1, b2, b3, out);
}

// Round 11
// 201.540 us; speedup vs baseline: 1.8736x; 1.8736x over previous
//
#include <hip/hip_runtime.h>
#include <math.h>

#define IDIM 32
#define KNN 16
#define NPTS 8192
#define NBATCH 16
#define PPB 16                      // points per block
#define CLAMPV 1.9f
#define TWO_OVER_PI 0.63661977236758134f

typedef __attribute__((ext_vector_type(8))) short bf16x8;   // 8 bf16 = 4 VGPR (MFMA A/B)
typedef __attribute__((ext_vector_type(4))) float f32x4;    // MFMA C/D
typedef __attribute__((ext_vector_type(2))) short s16x2;

// Compiler-friendly bf16 pack: scalar __bf16 casts fuse to v_cvt_pk_bf16_f32.
__device__ __forceinline__ unsigned pk2(float a, float b) {
    union { __bf16 h[2]; unsigned u; } r;
    r.h[0] = (__bf16)a; r.h[1] = (__bf16)b;
    return r.u;
}
__device__ __forceinline__ unsigned short f2bf(float f) {
    union { __bf16 h; unsigned short u; } r; r.h = (__bf16)f; return r.u;
}

// ReLU on a packed bf16 pair: IEEE sign-magnitude => per-half smax(x,0) == relu.
__device__ __forceinline__ unsigned relu2(unsigned p) {
    s16x2 v; __builtin_memcpy(&v, &p, 4);
    s16x2 z = {0, 0};
    s16x2 m = __builtin_elementwise_max(v, z);
    unsigned r; __builtin_memcpy(&r, &m, 4);
    return r;
}

// Raw ds_swizzle (BitMode XOR) — 1 DS op, no lane-index VALU math.
template<int PAT>
__device__ __forceinline__ float swzf(float v) {
    return __int_as_float(__builtin_amdgcn_ds_swizzle(__float_as_int(v), PAT));
}
__device__ __forceinline__ float red_max16(float o) {
    o = fmaxf(o, swzf<0x041F>(o));   // xor 1
    o = fmaxf(o, swzf<0x081F>(o));   // xor 2
    o = fmaxf(o, swzf<0x101F>(o));   // xor 4
    o = fmaxf(o, swzf<0x201F>(o));   // xor 8
    return o;
}
__device__ __forceinline__ float red_sum16(float o) {
    o += swzf<0x041F>(o); o += swzf<0x081F>(o);
    o += swzf<0x101F>(o); o += swzf<0x201F>(o);
    return o;
}

// ---------------------------------------------------------------------------
// Precompute MFMA A-fragments (bf16) for all 4 networks into ws.
// mfma_f32_16x16x32_bf16 A-layout: lane l holds A[row=l&15][k=(l>>4)*8+j], j=0..7.
// Frag f element order in ws: f*512 + lane*8 + j.
// Frag table per net u (fb = u*14):
//   fb+c        (c=0..3)        : L1  A_c[row][k] = W1f[k][16c+row]
//   fb+4+2c+kc  (c=0..3,kc=0..1): L2  A[row][k]   = W2[kc*32+k][16c+row]
//   fb+12+kc    (kc=0..1)       : L3  A[row][k]   = W3[kc*32+k][row]
// W1f rows: k<16 -> WA[k]=W1[k]-W1[32+k]; k>=16 -> WB[k-16]=W1[k]+W1[k+16]
// ---------------------------------------------------------------------------
__global__ void prep_frags(const float* __restrict__ W1, const float* __restrict__ W2,
                           const float* __restrict__ W3, unsigned short* __restrict__ wsb) {
    int e = blockIdx.x * 256 + threadIdx.x;       // 0 .. 56*512-1
    if (e >= 56 * 512) return;
    int f = e >> 9, idx = e & 511;
    int lane = idx >> 3, j = idx & 7;
    int row = lane & 15, g = lane >> 4;
    int k = g * 8 + j;                            // 0..31
    int u = f / 14, t = f % 14;
    float val;
    if (t < 4) {
        int h = 16 * t + row;
        const float* w = W1 + u * 3072;           // (48,64) row-major
        val = (k < 16) ? (w[k * 64 + h] - w[(32 + k) * 64 + h])
                       : (w[k * 64 + h] + w[(k + 16) * 64 + h]);
    } else if (t < 12) {
        int c = (t - 4) >> 1, kc = (t - 4) & 1;
        val = W2[u * 4096 + (kc * 32 + k) * 64 + 16 * c + row];
    } else {
        int kc = t - 12;
        val = W3[u * 1024 + (kc * 32 + k) * 16 + row];
    }
    wsb[e] = f2bf(val);
}

// ---------------------------------------------------------------------------
// z[b,n,d] = x[b,n,31-d]*exp(logs[d]) + bias[d]; init log_det[b].
// Also writes z1 (dims 0..15) pre-packed to bf16 (MFMA-ready) so the gather
// kernel loads 16B/lane with zero pack work.
// ---------------------------------------------------------------------------
__global__ void affine_rev(const float* __restrict__ x, const float* __restrict__ logs,
                           const float* __restrict__ bias, float* __restrict__ out,
                           unsigned short* __restrict__ z1bf) {
    __shared__ float ssc[IDIM], sbi[IDIM];
    int tid = threadIdx.x;
    if (tid < IDIM) { ssc[tid] = expf(logs[tid]); sbi[tid] = bias[tid]; }
    __syncthreads();
    size_t p = (size_t)blockIdx.x * blockDim.x + tid;
    if (p < (size_t)NBATCH * NPTS) {
        const float4* xr = (const float4*)(x + p * IDIM);
        float xv[IDIM];
#pragma unroll
        for (int q = 0; q < 8; ++q) {
            float4 v = xr[q];
            xv[q * 4 + 0] = v.x; xv[q * 4 + 1] = v.y; xv[q * 4 + 2] = v.z; xv[q * 4 + 3] = v.w;
        }
        float zv[IDIM];
#pragma unroll
        for (int d = 0; d < IDIM; ++d) zv[d] = xv[31 - d] * ssc[d] + sbi[d];
        float4* zr = (float4*)(out + p * IDIM);
#pragma unroll
        for (int q = 0; q < 8; ++q) {
            float4 v;
            v.x = zv[q * 4 + 0]; v.y = zv[q * 4 + 1];
            v.z = zv[q * 4 + 2]; v.w = zv[q * 4 + 3];
            zr[q] = v;
        }
        if (z1bf) {
            union { uint4 q[2]; unsigned w[8]; } pk;
#pragma unroll
            for (int d = 0; d < 8; ++d) pk.w[d] = pk2(zv[2 * d], zv[2 * d + 1]);
            uint4* zp = (uint4*)(z1bf + p * 16);
            zp[0] = pk.q[0]; zp[1] = pk.q[1];
        }
    }
    if (blockIdx.x == 0 && tid < NBATCH) {
        float sl = 0.f;
#pragma unroll
        for (int d = 0; d < IDIM; ++d) sl += logs[d];
        out[(size_t)NBATCH * NPTS * IDIM + tid] = sl * (float)NPTS;
    }
}

// ---------------------------------------------------------------------------
// MFMA conv kernel, 2-pt ILP + feature prefetch.
// r11 = r9 LDS layout (stride 17 u64 = 136B: 34 dwords ≡ 2 mod 32 -> 16 lanes
// spread over all banks, conflict-free; fragment reads as 2x ds_read_b64.
// Stride 18 (r10) was 36 dwords ≡ 4 mod 32 -> 4-way conflict, 578x counter
// blowup, +160 µs) + r10's pre-packed bf16 z1 gather (proven: FETCH 62->29 MB).
// ---------------------------------------------------------------------------
__global__ __launch_bounds__(256, 3)
void knn_mfma(const int* __restrict__ knn, const unsigned short* __restrict__ wsb,
              const unsigned short* __restrict__ z1b,
              const float* __restrict__ B1, const float* __restrict__ B2,
              const float* __restrict__ B3, float* __restrict__ out) {
    __shared__ unsigned long long hq[4 * 2 * 272];        // [wave][ptA/B][16 x 17]
    __shared__ float stg[PPB * 4 * 16];                   // [pt][net][dim]
    __shared__ float ldsum[16];
    __shared__ int   sidx[PPB * KNN];                     // 256 knn indices for this block

    const int tid = threadIdx.x;
    const int u = tid >> 6, lane = tid & 63;
    const int g = lane >> 4, x = lane & 15;
    const int pbase = blockIdx.x * PPB;
    const int bb = pbase >> 13;                           // batch (PPB divides 8192)

    // --- stage knn indices (one coalesced load per thread) ---
    sidx[tid] = knn[(size_t)pbase * KNN + tid];

    // --- weight fragments (persist across the point loop) ---
    bf16x8 a1[4], a2k0[4], a2k1[4], a30, a31;
    const int fb = u * 14;
#pragma unroll
    for (int c = 0; c < 4; ++c)
        a1[c] = *(const bf16x8*)(wsb + (size_t)(fb + c) * 512 + lane * 8);
#pragma unroll
    for (int c = 0; c < 4; ++c) {
        a2k0[c] = *(const bf16x8*)(wsb + (size_t)(fb + 4 + 2 * c + 0) * 512 + lane * 8);
        a2k1[c] = *(const bf16x8*)(wsb + (size_t)(fb + 4 + 2 * c + 1) * 512 + lane * 8);
    }
    a30 = *(const bf16x8*)(wsb + (size_t)(fb + 12) * 512 + lane * 8);
    a31 = *(const bf16x8*)(wsb + (size_t)(fb + 13) * 512 + lane * 8);

    // --- biases as persistent MFMA C-operands: lane owns rows 16c+4g..+3 ---
    f32x4 b1v[4], b2v[4], b3v;
#pragma unroll
    for (int c = 0; c < 4; ++c) {
        b1v[c] = *(const f32x4*)(B1 + u * 64 + 16 * c + 4 * g);
        b2v[c] = *(const f32x4*)(B2 + u * 64 + 16 * c + 4 * g);
    }
    b3v = *(const f32x4*)(B3 + u * 16 + 4 * g);

    // --- LDS staging offsets in u64 units; stride 17; swizzle even ---
    const int baseA = (u * 2 + 0) * 272;
    const int baseB = (u * 2 + 1) * 272;
    const int swq = (x & 7) << 1;
    int woq[4];
#pragma unroll
    for (int c = 0; c < 4; ++c) woq[c] = x * 17 + ((4 * c + g) ^ swq);
    const int rq0 = x * 17 + ((2 * g) ^ swq);
    const int rq1 = x * 17 + ((8 + 2 * g) ^ swq);

    const int off = (g & 1) * 8;
    const unsigned short* z1p = z1b + (size_t)bb * NPTS * 16;  // packed z1 base
    const int baseRow = pbase & (NPTS - 1);               // local row of pbase

    __syncthreads();                                      // sidx visible

    // --- prologue: features for pair 0 ---
    union fu { bf16x8 v; uint4 q; unsigned long long ql[2]; };
    uint4 pAq, pBq, nAq, nBq;
    {
        int iA0 = sidx[x], iB0 = sidx[16 + x];
        int rA = (g < 2) ? baseRow : iA0;
        int rB = (g < 2) ? (baseRow + 1) : iB0;
        pAq = *(const uint4*)(z1p + (size_t)rA * 16 + off);
        pBq = *(const uint4*)(z1p + (size_t)rB * 16 + off);
    }

#pragma unroll 2
    for (int pp = 0; pp < PPB / 2; ++pp) {
        // prefetch next pair's features (indices from LDS, just-in-time)
        if (pp < PPB / 2 - 1) {
            int iA1 = sidx[(2 * pp + 2) * 16 + x];
            int iB1 = sidx[(2 * pp + 3) * 16 + x];
            int rA = (g < 2) ? (baseRow + 2 * pp + 2) : iA1;
            int rB = (g < 2) ? (baseRow + 2 * pp + 3) : iB1;
            nAq = *(const uint4*)(z1p + (size_t)rA * 16 + off);
            nBq = *(const uint4*)(z1p + (size_t)rB * 16 + off);
        }

        // features as MFMA B-fragments (already bf16-packed)
        fu efA, efB;
        efA.q = pAq; efB.q = pBq;

        // ---- L1 (bias in C) ----
        f32x4 aA[4], aB[4];
        __builtin_amdgcn_s_setprio(1);
#pragma unroll
        for (int c = 0; c < 4; ++c)
            aA[c] = __builtin_amdgcn_mfma_f32_16x16x32_bf16(a1[c], efA.v, b1v[c], 0, 0, 0);
#pragma unroll
        for (int c = 0; c < 4; ++c)
            aB[c] = __builtin_amdgcn_mfma_f32_16x16x32_bf16(a1[c], efB.v, b1v[c], 0, 0, 0);
        __builtin_amdgcn_s_setprio(0);
#pragma unroll
        for (int c = 0; c < 4; ++c) {
            union { unsigned w[2]; unsigned long long q; } qa;
            qa.w[0] = relu2(pk2(aA[c][0], aA[c][1]));
            qa.w[1] = relu2(pk2(aA[c][2], aA[c][3]));
            hq[baseA + woq[c]] = qa.q;
        }
#pragma unroll
        for (int c = 0; c < 4; ++c) {
            union { unsigned w[2]; unsigned long long q; } qb;
            qb.w[0] = relu2(pk2(aB[c][0], aB[c][1]));
            qb.w[1] = relu2(pk2(aB[c][2], aB[c][3]));
            hq[baseB + woq[c]] = qb.q;
        }

        // ---- read h1, L2 (bias in C) ----
        fu h0A, h1A, h0B, h1B;
        h0A.ql[0] = hq[baseA + rq0]; h0A.ql[1] = hq[baseA + rq0 + 1];
        h1A.ql[0] = hq[baseA + rq1]; h1A.ql[1] = hq[baseA + rq1 + 1];
        h0B.ql[0] = hq[baseB + rq0]; h0B.ql[1] = hq[baseB + rq0 + 1];
        h1B.ql[0] = hq[baseB + rq1]; h1B.ql[1] = hq[baseB + rq1 + 1];
        f32x4 cA[4], cB[4];
        __builtin_amdgcn_s_setprio(1);
#pragma unroll
        for (int c = 0; c < 4; ++c) {
            cA[c] = __builtin_amdgcn_mfma_f32_16x16x32_bf16(a2k0[c], h0A.v, b2v[c], 0, 0, 0);
            cB[c] = __builtin_amdgcn_mfma_f32_16x16x32_bf16(a2k0[c], h0B.v, b2v[c], 0, 0, 0);
        }
#pragma unroll
        for (int c = 0; c < 4; ++c) {
            cA[c] = __builtin_amdgcn_mfma_f32_16x16x32_bf16(a2k1[c], h1A.v, cA[c], 0, 0, 0);
            cB[c] = __builtin_amdgcn_mfma_f32_16x16x32_bf16(a2k1[c], h1B.v, cB[c], 0, 0, 0);
        }
        __builtin_amdgcn_s_setprio(0);
#pragma unroll
        for (int c = 0; c < 4; ++c) {
            union { unsigned w[2]; unsigned long long q; } qa;
            qa.w[0] = relu2(pk2(cA[c][0], cA[c][1]));
            qa.w[1] = relu2(pk2(cA[c][2], cA[c][3]));
            hq[baseA + woq[c]] = qa.q;
        }
#pragma unroll
        for (int c = 0; c < 4; ++c) {
            union { unsigned w[2]; unsigned long long q; } qb;
            qb.w[0] = relu2(pk2(cB[c][0], cB[c][1]));
            qb.w[1] = relu2(pk2(cB[c][2], cB[c][3]));
            hq[baseB + woq[c]] = qb.q;
        }

        // ---- read h2, L3 (bias in C) ----
        fu g0A, g1A, g0B, g1B;
        g0A.ql[0] = hq[baseA + rq0]; g0A.ql[1] = hq[baseA + rq0 + 1];
        g1A.ql[0] = hq[baseA + rq1]; g1A.ql[1] = hq[baseA + rq1 + 1];
        g0B.ql[0] = hq[baseB + rq0]; g0B.ql[1] = hq[baseB + rq0 + 1];
        g1B.ql[0] = hq[baseB + rq1]; g1B.ql[1] = hq[baseB + rq1 + 1];
        f32x4 oA, oB;
        __builtin_amdgcn_s_setprio(1);
        oA = __builtin_amdgcn_mfma_f32_16x16x32_bf16(a30, g0A.v, b3v, 0, 0, 0);
        oB = __builtin_amdgcn_mfma_f32_16x16x32_bf16(a30, g0B.v, b3v, 0, 0, 0);
        oA = __builtin_amdgcn_mfma_f32_16x16x32_bf16(a31, g1A.v, oA, 0, 0, 0);
        oB = __builtin_amdgcn_mfma_f32_16x16x32_bf16(a31, g1B.v, oB, 0, 0, 0);
        __builtin_amdgcn_s_setprio(0);

        // max over neighbors: raw ds_swizzle XOR tree
        float oA0 = red_max16(oA[0]), oA1 = red_max16(oA[1]);
        float oA2 = red_max16(oA[2]), oA3 = red_max16(oA[3]);
        float oB0 = red_max16(oB[0]), oB1 = red_max16(oB[1]);
        float oB2 = red_max16(oB[2]), oB3 = red_max16(oB[3]);

        if (x == 0) {
            *(float4*)&stg[((2 * pp + 0) * 4 + u) * 16 + 4 * g] = make_float4(oA0, oA1, oA2, oA3);
            *(float4*)&stg[((2 * pp + 1) * 4 + u) * 16 + 4 * g] = make_float4(oB0, oB1, oB2, oB3);
        }

        // rotate prefetched features
        pAq = nAq; pBq = nBq;
    }
    __syncthreads();

    // --- epilogue: z2 update + log_det (one atomic per block) ---
    {
        const int pu = u * 4 + g;                  // 0..15
        const int prow = pbase + pu;
        const size_t zoff = (size_t)prow * IDIM + 16 + x;
        float z2v = out[zoff];
        float s1 = stg[(pu * 4 + 0) * 16 + x];
        float t1 = stg[(pu * 4 + 1) * 16 + x];
        float s2 = stg[(pu * 4 + 2) * 16 + x];
        float t2 = stg[(pu * 4 + 3) * 16 + x];
        float sc1 = CLAMPV * TWO_OVER_PI * atanf(s1 * (1.0f / CLAMPV));
        float sc2 = CLAMPV * TWO_OVER_PI * atanf(s2 * (1.0f / CLAMPV));
        z2v = z2v * expf(sc1) + t1;
        z2v = z2v * expf(sc2) + t2;
        out[zoff] = z2v;
        float ss = red_sum16(sc1 + sc2);
        if (x == 0) ldsum[pu] = ss;
    }
    __syncthreads();
    if (tid == 0) {
        float tot = 0.f;
#pragma unroll
        for (int i = 0; i < 16; ++i) tot += ldsum[i];
        atomicAdd(out + (size_t)NBATCH * NPTS * IDIM + bb, tot);
    }
}

extern "C" void kernel_launch(void* const* d_in, const int* in_sizes, int n_in,
                              void* d_out, int out_size, void* d_ws, size_t ws_size,
                              hipStream_t stream) {
    const float* x    = (const float*)d_in[0];
    const int*   knn  = (const int*)d_in[1];
    const float* logs = (const float*)d_in[2];
    const float* bias = (const float*)d_in[3];
    const float* W1   = (const float*)d_in[4];
    const float* b1   = (const float*)d_in[5];
    const float* W2   = (const float*)d_in[6];
    const float* b2   = (const float*)d_in[7];
    const float* W3   = (const float*)d_in[8];
    const float* b3   = (const float*)d_in[9];
    float* out = (float*)d_out;
    unsigned short* wsb = (unsigned short*)d_ws;   // frags: 56*512 shorts = 57344 B
    unsigned short* z1bf = wsb + 56 * 512;         // packed z1: 4 MB (ws is ample)

    hipLaunchKernelGGL(prep_frags, dim3(112), dim3(256), 0, stream, W1, W2, W3, wsb);
    hipLaunchKernelGGL(affine_rev, dim3(512), dim3(256), 0, stream, x, logs, bias, out, z1bf);
    hipLaunchKernelGGL(knn_mfma, dim3((NBATCH * NPTS) / PPB), dim3(256), 0, stream,
                       knn, wsb, z1bf, b1, b2, b3, out);
}

// Round 12
// 190.048 us; speedup vs baseline: 1.9869x; 1.0605x over previous
//
#include <hip/hip_runtime.h>
#include <math.h>

#define IDIM 32
#define KNN 16
#define NPTS 8192
#define NBATCH 16
#define PPB 16                      // points per block
#define CLAMPV 1.9f
#define TWO_OVER_PI 0.63661977236758134f

typedef __attribute__((ext_vector_type(8))) short bf16x8;   // 8 bf16 = 4 VGPR (MFMA A/B)
typedef __attribute__((ext_vector_type(4))) float f32x4;    // MFMA C/D
typedef __attribute__((ext_vector_type(2))) short s16x2;

// Compiler-friendly bf16 pack: scalar __bf16 casts fuse to v_cvt_pk_bf16_f32.
__device__ __forceinline__ unsigned pk2(float a, float b) {
    union { __bf16 h[2]; unsigned u; } r;
    r.h[0] = (__bf16)a; r.h[1] = (__bf16)b;
    return r.u;
}
__device__ __forceinline__ unsigned short f2bf(float f) {
    union { __bf16 h; unsigned short u; } r; r.h = (__bf16)f; return r.u;
}

// ReLU on a packed bf16 pair: IEEE sign-magnitude => per-half smax(x,0) == relu.
__device__ __forceinline__ unsigned relu2(unsigned p) {
    s16x2 v; __builtin_memcpy(&v, &p, 4);
    s16x2 z = {0, 0};
    s16x2 m = __builtin_elementwise_max(v, z);
    unsigned r; __builtin_memcpy(&r, &m, 4);
    return r;
}

// DPP row-rotate within the 16-lane row (our k-group): VALU-only cross-lane,
// replaces ds_swizzle (DS pipe + lgkmcnt stalls) in the reductions.
// ctrl: row_ror:N = 0x120|N.
template<int CTRL>
__device__ __forceinline__ float dppf(float v) {
    return __int_as_float(__builtin_amdgcn_update_dpp(
        0, __float_as_int(v), CTRL, 0xF, 0xF, true));
}
// Rotation butterfly (8,4,2,1): every lane accumulates all 16 values.
__device__ __forceinline__ float red_max16(float o) {
    o = fmaxf(o, dppf<0x128>(o));   // row_ror:8
    o = fmaxf(o, dppf<0x124>(o));   // row_ror:4
    o = fmaxf(o, dppf<0x122>(o));   // row_ror:2
    o = fmaxf(o, dppf<0x121>(o));   // row_ror:1
    return o;
}
__device__ __forceinline__ float red_sum16(float o) {
    o += dppf<0x128>(o); o += dppf<0x124>(o);
    o += dppf<0x122>(o); o += dppf<0x121>(o);
    return o;
}

// ---------------------------------------------------------------------------
// Precompute MFMA A-fragments (bf16) for all 4 networks into ws.
// mfma_f32_16x16x32_bf16 A-layout: lane l holds A[row=l&15][k=(l>>4)*8+j], j=0..7.
// Frag f element order in ws: f*512 + lane*8 + j.
// Frag table per net u (fb = u*14):
//   fb+c        (c=0..3)        : L1  A_c[row][k] = W1f[k][16c+row]
//   fb+4+2c+kc  (c=0..3,kc=0..1): L2  A[row][k]   = W2[kc*32+k][16c+row]
//   fb+12+kc    (kc=0..1)       : L3  A[row][k]   = W3[kc*32+k][row]
// W1f rows: k<16 -> WA[k]=W1[k]-W1[32+k]; k>=16 -> WB[k-16]=W1[k]+W1[k+16]
// ---------------------------------------------------------------------------
__global__ void prep_frags(const float* __restrict__ W1, const float* __restrict__ W2,
                           const float* __restrict__ W3, unsigned short* __restrict__ wsb) {
    int e = blockIdx.x * 256 + threadIdx.x;       // 0 .. 56*512-1
    if (e >= 56 * 512) return;
    int f = e >> 9, idx = e & 511;
    int lane = idx >> 3, j = idx & 7;
    int row = lane & 15, g = lane >> 4;
    int k = g * 8 + j;                            // 0..31
    int u = f / 14, t = f % 14;
    float val;
    if (t < 4) {
        int h = 16 * t + row;
        const float* w = W1 + u * 3072;           // (48,64) row-major
        val = (k < 16) ? (w[k * 64 + h] - w[(32 + k) * 64 + h])
                       : (w[k * 64 + h] + w[(k + 16) * 64 + h]);
    } else if (t < 12) {
        int c = (t - 4) >> 1, kc = (t - 4) & 1;
        val = W2[u * 4096 + (kc * 32 + k) * 64 + 16 * c + row];
    } else {
        int kc = t - 12;
        val = W3[u * 1024 + (kc * 32 + k) * 16 + row];
    }
    wsb[e] = f2bf(val);
}

// ---------------------------------------------------------------------------
// z[b,n,d] = x[b,n,31-d]*exp(logs[d]) + bias[d]; init log_det[b].
// Also writes z1 (dims 0..15) pre-packed to bf16 (MFMA-ready) so the gather
// kernel loads 16B/lane with zero pack work.
// ---------------------------------------------------------------------------
__global__ void affine_rev(const float* __restrict__ x, const float* __restrict__ logs,
                           const float* __restrict__ bias, float* __restrict__ out,
                           unsigned short* __restrict__ z1bf) {
    __shared__ float ssc[IDIM], sbi[IDIM];
    int tid = threadIdx.x;
    if (tid < IDIM) { ssc[tid] = expf(logs[tid]); sbi[tid] = bias[tid]; }
    __syncthreads();
    size_t p = (size_t)blockIdx.x * blockDim.x + tid;
    if (p < (size_t)NBATCH * NPTS) {
        const float4* xr = (const float4*)(x + p * IDIM);
        float xv[IDIM];
#pragma unroll
        for (int q = 0; q < 8; ++q) {
            float4 v = xr[q];
            xv[q * 4 + 0] = v.x; xv[q * 4 + 1] = v.y; xv[q * 4 + 2] = v.z; xv[q * 4 + 3] = v.w;
        }
        float zv[IDIM];
#pragma unroll
        for (int d = 0; d < IDIM; ++d) zv[d] = xv[31 - d] * ssc[d] + sbi[d];
        float4* zr = (float4*)(out + p * IDIM);
#pragma unroll
        for (int q = 0; q < 8; ++q) {
            float4 v;
            v.x = zv[q * 4 + 0]; v.y = zv[q * 4 + 1];
            v.z = zv[q * 4 + 2]; v.w = zv[q * 4 + 3];
            zr[q] = v;
        }
        if (z1bf) {
            union { uint4 q[2]; unsigned w[8]; } pk;
#pragma unroll
            for (int d = 0; d < 8; ++d) pk.w[d] = pk2(zv[2 * d], zv[2 * d + 1]);
            uint4* zp = (uint4*)(z1bf + p * 16);
            zp[0] = pk.q[0]; zp[1] = pk.q[1];
        }
    }
    if (blockIdx.x == 0 && tid < NBATCH) {
        float sl = 0.f;
#pragma unroll
        for (int d = 0; d < IDIM; ++d) sl += logs[d];
        out[(size_t)NBATCH * NPTS * IDIM + tid] = sl * (float)NPTS;
    }
}

// ---------------------------------------------------------------------------
// MFMA conv kernel, 2-pt ILP + feature prefetch.
// r12 = r11 (stride-17 LDS, bf16 z1 gather, unroll-2, setprio, bias-in-C)
// with all 16-lane reductions moved from ds_swizzle (DS pipe, lgkmcnt-stalled
// 4-deep chains) to DPP row_ror (VALU-only, zero DS ops).
// ---------------------------------------------------------------------------
__global__ __launch_bounds__(256, 3)
void knn_mfma(const int* __restrict__ knn, const unsigned short* __restrict__ wsb,
              const unsigned short* __restrict__ z1b,
              const float* __restrict__ B1, const float* __restrict__ B2,
              const float* __restrict__ B3, float* __restrict__ out) {
    __shared__ unsigned long long hq[4 * 2 * 272];        // [wave][ptA/B][16 x 17]
    __shared__ float stg[PPB * 4 * 16];                   // [pt][net][dim]
    __shared__ float ldsum[16];
    __shared__ int   sidx[PPB * KNN];                     // 256 knn indices for this block

    const int tid = threadIdx.x;
    const int u = tid >> 6, lane = tid & 63;
    const int g = lane >> 4, x = lane & 15;
    const int pbase = blockIdx.x * PPB;
    const int bb = pbase >> 13;                           // batch (PPB divides 8192)

    // --- stage knn indices (one coalesced load per thread) ---
    sidx[tid] = knn[(size_t)pbase * KNN + tid];

    // --- weight fragments (persist across the point loop) ---
    bf16x8 a1[4], a2k0[4], a2k1[4], a30, a31;
    const int fb = u * 14;
#pragma unroll
    for (int c = 0; c < 4; ++c)
        a1[c] = *(const bf16x8*)(wsb + (size_t)(fb + c) * 512 + lane * 8);
#pragma unroll
    for (int c = 0; c < 4; ++c) {
        a2k0[c] = *(const bf16x8*)(wsb + (size_t)(fb + 4 + 2 * c + 0) * 512 + lane * 8);
        a2k1[c] = *(const bf16x8*)(wsb + (size_t)(fb + 4 + 2 * c + 1) * 512 + lane * 8);
    }
    a30 = *(const bf16x8*)(wsb + (size_t)(fb + 12) * 512 + lane * 8);
    a31 = *(const bf16x8*)(wsb + (size_t)(fb + 13) * 512 + lane * 8);

    // --- biases as persistent MFMA C-operands: lane owns rows 16c+4g..+3 ---
    f32x4 b1v[4], b2v[4], b3v;
#pragma unroll
    for (int c = 0; c < 4; ++c) {
        b1v[c] = *(const f32x4*)(B1 + u * 64 + 16 * c + 4 * g);
        b2v[c] = *(const f32x4*)(B2 + u * 64 + 16 * c + 4 * g);
    }
    b3v = *(const f32x4*)(B3 + u * 16 + 4 * g);

    // --- LDS staging offsets in u64 units; stride 17; swizzle even ---
    const int baseA = (u * 2 + 0) * 272;
    const int baseB = (u * 2 + 1) * 272;
    const int swq = (x & 7) << 1;
    int woq[4];
#pragma unroll
    for (int c = 0; c < 4; ++c) woq[c] = x * 17 + ((4 * c + g) ^ swq);
    const int rq0 = x * 17 + ((2 * g) ^ swq);
    const int rq1 = x * 17 + ((8 + 2 * g) ^ swq);

    const int off = (g & 1) * 8;
    const unsigned short* z1p = z1b + (size_t)bb * NPTS * 16;  // packed z1 base
    const int baseRow = pbase & (NPTS - 1);               // local row of pbase

    __syncthreads();                                      // sidx visible

    // --- prologue: features for pair 0 ---
    union fu { bf16x8 v; uint4 q; unsigned long long ql[2]; };
    uint4 pAq, pBq, nAq, nBq;
    {
        int iA0 = sidx[x], iB0 = sidx[16 + x];
        int rA = (g < 2) ? baseRow : iA0;
        int rB = (g < 2) ? (baseRow + 1) : iB0;
        pAq = *(const uint4*)(z1p + (size_t)rA * 16 + off);
        pBq = *(const uint4*)(z1p + (size_t)rB * 16 + off);
    }

#pragma unroll 2
    for (int pp = 0; pp < PPB / 2; ++pp) {
        // prefetch next pair's features (indices from LDS, just-in-time)
        if (pp < PPB / 2 - 1) {
            int iA1 = sidx[(2 * pp + 2) * 16 + x];
            int iB1 = sidx[(2 * pp + 3) * 16 + x];
            int rA = (g < 2) ? (baseRow + 2 * pp + 2) : iA1;
            int rB = (g < 2) ? (baseRow + 2 * pp + 3) : iB1;
            nAq = *(const uint4*)(z1p + (size_t)rA * 16 + off);
            nBq = *(const uint4*)(z1p + (size_t)rB * 16 + off);
        }

        // features as MFMA B-fragments (already bf16-packed)
        fu efA, efB;
        efA.q = pAq; efB.q = pBq;

        // ---- L1 (bias in C) ----
        f32x4 aA[4], aB[4];
        __builtin_amdgcn_s_setprio(1);
#pragma unroll
        for (int c = 0; c < 4; ++c)
            aA[c] = __builtin_amdgcn_mfma_f32_16x16x32_bf16(a1[c], efA.v, b1v[c], 0, 0, 0);
#pragma unroll
        for (int c = 0; c < 4; ++c)
            aB[c] = __builtin_amdgcn_mfma_f32_16x16x32_bf16(a1[c], efB.v, b1v[c], 0, 0, 0);
        __builtin_amdgcn_s_setprio(0);
#pragma unroll
        for (int c = 0; c < 4; ++c) {
            union { unsigned w[2]; unsigned long long q; } qa;
            qa.w[0] = relu2(pk2(aA[c][0], aA[c][1]));
            qa.w[1] = relu2(pk2(aA[c][2], aA[c][3]));
            hq[baseA + woq[c]] = qa.q;
        }
#pragma unroll
        for (int c = 0; c < 4; ++c) {
            union { unsigned w[2]; unsigned long long q; } qb;
            qb.w[0] = relu2(pk2(aB[c][0], aB[c][1]));
            qb.w[1] = relu2(pk2(aB[c][2], aB[c][3]));
            hq[baseB + woq[c]] = qb.q;
        }

        // ---- read h1, L2 (bias in C) ----
        fu h0A, h1A, h0B, h1B;
        h0A.ql[0] = hq[baseA + rq0]; h0A.ql[1] = hq[baseA + rq0 + 1];
        h1A.ql[0] = hq[baseA + rq1]; h1A.ql[1] = hq[baseA + rq1 + 1];
        h0B.ql[0] = hq[baseB + rq0]; h0B.ql[1] = hq[baseB + rq0 + 1];
        h1B.ql[0] = hq[baseB + rq1]; h1B.ql[1] = hq[baseB + rq1 + 1];
        f32x4 cA[4], cB[4];
        __builtin_amdgcn_s_setprio(1);
#pragma unroll
        for (int c = 0; c < 4; ++c) {
            cA[c] = __builtin_amdgcn_mfma_f32_16x16x32_bf16(a2k0[c], h0A.v, b2v[c], 0, 0, 0);
            cB[c] = __builtin_amdgcn_mfma_f32_16x16x32_bf16(a2k0[c], h0B.v, b2v[c], 0, 0, 0);
        }
#pragma unroll
        for (int c = 0; c < 4; ++c) {
            cA[c] = __builtin_amdgcn_mfma_f32_16x16x32_bf16(a2k1[c], h1A.v, cA[c], 0, 0, 0);
            cB[c] = __builtin_amdgcn_mfma_f32_16x16x32_bf16(a2k1[c], h1B.v, cB[c], 0, 0, 0);
        }
        __builtin_amdgcn_s_setprio(0);
#pragma unroll
        for (int c = 0; c < 4; ++c) {
            union { unsigned w[2]; unsigned long long q; } qa;
            qa.w[0] = relu2(pk2(cA[c][0], cA[c][1]));
            qa.w[1] = relu2(pk2(cA[c][2], cA[c][3]));
            hq[baseA + woq[c]] = qa.q;
        }
#pragma unroll
        for (int c = 0; c < 4; ++c) {
            union { unsigned w[2]; unsigned long long q; } qb;
            qb.w[0] = relu2(pk2(cB[c][0], cB[c][1]));
            qb.w[1] = relu2(pk2(cB[c][2], cB[c][3]));
            hq[baseB + woq[c]] = qb.q;
        }

        // ---- read h2, L3 (bias in C) ----
        fu g0A, g1A, g0B, g1B;
        g0A.ql[0] = hq[baseA + rq0]; g0A.ql[1] = hq[baseA + rq0 + 1];
        g1A.ql[0] = hq[baseA + rq1]; g1A.ql[1] = hq[baseA + rq1 + 1];
        g0B.ql[0] = hq[baseB + rq0]; g0B.ql[1] = hq[baseB + rq0 + 1];
        g1B.ql[0] = hq[baseB + rq1]; g1B.ql[1] = hq[baseB + rq1 + 1];
        f32x4 oA, oB;
        __builtin_amdgcn_s_setprio(1);
        oA = __builtin_amdgcn_mfma_f32_16x16x32_bf16(a30, g0A.v, b3v, 0, 0, 0);
        oB = __builtin_amdgcn_mfma_f32_16x16x32_bf16(a30, g0B.v, b3v, 0, 0, 0);
        oA = __builtin_amdgcn_mfma_f32_16x16x32_bf16(a31, g1A.v, oA, 0, 0, 0);
        oB = __builtin_amdgcn_mfma_f32_16x16x32_bf16(a31, g1B.v, oB, 0, 0, 0);
        __builtin_amdgcn_s_setprio(0);

        // max over neighbors: DPP row_ror butterfly (VALU-only)
        float oA0 = red_max16(oA[0]), oA1 = red_max16(oA[1]);
        float oA2 = red_max16(oA[2]), oA3 = red_max16(oA[3]);
        float oB0 = red_max16(oB[0]), oB1 = red_max16(oB[1]);
        float oB2 = red_max16(oB[2]), oB3 = red_max16(oB[3]);

        if (x == 0) {
            *(float4*)&stg[((2 * pp + 0) * 4 + u) * 16 + 4 * g] = make_float4(oA0, oA1, oA2, oA3);
            *(float4*)&stg[((2 * pp + 1) * 4 + u) * 16 + 4 * g] = make_float4(oB0, oB1, oB2, oB3);
        }

        // rotate prefetched features
        pAq = nAq; pBq = nBq;
    }
    __syncthreads();

    // --- epilogue: z2 update + log_det (one atomic per block) ---
    {
        const int pu = u * 4 + g;                  // 0..15
        const int prow = pbase + pu;
        const size_t zoff = (size_t)prow * IDIM + 16 + x;
        float z2v = out[zoff];
        float s1 = stg[(pu * 4 + 0) * 16 + x];
        float t1 = stg[(pu * 4 + 1) * 16 + x];
        float s2 = stg[(pu * 4 + 2) * 16 + x];
        float t2 = stg[(pu * 4 + 3) * 16 + x];
        float sc1 = CLAMPV * TWO_OVER_PI * atanf(s1 * (1.0f / CLAMPV));
        float sc2 = CLAMPV * TWO_OVER_PI * atanf(s2 * (1.0f / CLAMPV));
        z2v = z2v * expf(sc1) + t1;
        z2v = z2v * expf(sc2) + t2;
        out[zoff] = z2v;
        float ss = red_sum16(sc1 + sc2);
        if (x == 0) ldsum[pu] = ss;
    }
    __syncthreads();
    if (tid == 0) {
        float tot = 0.f;
#pragma unroll
        for (int i = 0; i < 16; ++i) tot += ldsum[i];
        atomicAdd(out + (size_t)NBATCH * NPTS * IDIM + bb, tot);
    }
}

extern "C" void kernel_launch(void* const* d_in, const int* in_sizes, int n_in,
                              void* d_out, int out_size, void* d_ws, size_t ws_size,
                              hipStream_t stream) {
    const float* x    = (const float*)d_in[0];
    const int*   knn  = (const int*)d_in[1];
    const float* logs = (const float*)d_in[2];
    const float* bias = (const float*)d_in[3];
    const float* W1   = (const float*)d_in[4];
    const float* b1   = (const float*)d_in[5];
    const float* W2   = (const float*)d_in[6];
    const float* b2   = (const float*)d_in[7];
    const float* W3   = (const float*)d_in[8];
    const float* b3   = (const float*)d_in[9];
    float* out = (float*)d_out;
    unsigned short* wsb = (unsigned short*)d_ws;   // frags: 56*512 shorts = 57344 B
    unsigned short* z1bf = wsb + 56 * 512;         // packed z1: 4 MB (ws is ample)

    hipLaunchKernelGGL(prep_frags, dim3(112), dim3(256), 0, stream, W1, W2, W3, wsb);
    hipLaunchKernelGGL(affine_rev, dim3(512), dim3(256), 0, stream, x, logs, bias, out, z1bf);
    hipLaunchKernelGGL(knn_mfma, dim3((NBATCH * NPTS) / PPB), dim3(256), 0, stream,
                       knn, wsb, z1bf, b1, b2, b3, out);
}

// Round 14
// 172.609 us; speedup vs baseline: 2.1876x; 1.1010x over previous
//
#include <hip/hip_runtime.h>
#include <math.h>

#define IDIM 32
#define KNN 16
#define NPTS 8192
#define NBATCH 16
#define PPB 16                      // points per block
#define CLAMPV 1.9f
#define TWO_OVER_PI 0.63661977236758134f

typedef __attribute__((ext_vector_type(8))) short bf16x8;   // 8 bf16 = 4 VGPR (MFMA A/B)
typedef __attribute__((ext_vector_type(4))) float f32x4;    // MFMA C/D
typedef __attribute__((ext_vector_type(2))) short s16x2;

// Compiler-friendly bf16 pack: scalar __bf16 casts fuse to v_cvt_pk_bf16_f32.
__device__ __forceinline__ unsigned pk2(float a, float b) {
    union { __bf16 h[2]; unsigned u; } r;
    r.h[0] = (__bf16)a; r.h[1] = (__bf16)b;
    return r.u;
}
__device__ __forceinline__ unsigned short f2bf(float f) {
    union { __bf16 h; unsigned short u; } r; r.h = (__bf16)f; return r.u;
}

// ReLU on a packed bf16 pair: IEEE sign-magnitude => per-half smax(x,0) == relu.
__device__ __forceinline__ unsigned relu2(unsigned p) {
    s16x2 v; __builtin_memcpy(&v, &p, 4);
    s16x2 z = {0, 0};
    s16x2 m = __builtin_elementwise_max(v, z);
    unsigned r; __builtin_memcpy(&r, &m, 4);
    return r;
}

// DPP row-rotate within the 16-lane row (our k-group): VALU-only cross-lane.
template<int CTRL>
__device__ __forceinline__ float dppf(float v) {
    return __int_as_float(__builtin_amdgcn_update_dpp(
        0, __float_as_int(v), CTRL, 0xF, 0xF, true));
}
// Rotation butterfly (8,4,2,1): every lane accumulates all 16 values.
__device__ __forceinline__ float red_max16(float o) {
    o = fmaxf(o, dppf<0x128>(o));   // row_ror:8
    o = fmaxf(o, dppf<0x124>(o));   // row_ror:4
    o = fmaxf(o, dppf<0x122>(o));   // row_ror:2
    o = fmaxf(o, dppf<0x121>(o));   // row_ror:1
    return o;
}
__device__ __forceinline__ float red_sum16(float o) {
    o += dppf<0x128>(o); o += dppf<0x124>(o);
    o += dppf<0x122>(o); o += dppf<0x121>(o);
    return o;
}

// ---------------------------------------------------------------------------
// Precompute MFMA A-fragments (bf16) for all 4 networks into ws.
// A-layout: lane l holds A[row=l&15][k=(l>>4)*8+j], j=0..7; ws order
// f*512 + lane*8 + j.
//
// k-PERMUTATION FUSION: the MFMA contraction index k may be arbitrarily
// permuted if A and B agree. We choose pi(g,j) = 32*kf + 16*(j>>2) + 4g + (j&3)
// so that layer L's B-fragment in lane 16g+x is EXACTLY the relu-packed D
// values that lane already holds from layer L-1 (D-layout: rows 16c+4g+i,
// col x; frag kf=0 <- chunks c=0,1; kf=1 <- c=2,3). The permutation is folded
// into W2/W3's A-fragments here, eliminating the inter-layer LDS transpose.
// Frag table per net u (fb = u*14):
//   fb+c        (c=0..3)        : L1  A[row][k] = W1f[k][16c+row]   (k as-is)
//   fb+4+2c+kf  (c=0..3,kf=0..1): L2  A[row][8g+j] = W2[pi(g,j)][16c+row]
//   fb+12+kf    (kf=0..1)       : L3  A[row][8g+j] = W3[pi(g,j)][row]
// W1f rows: k<16 -> WA[k]=W1[k]-W1[32+k]; k>=16 -> WB[k-16]=W1[k]+W1[k+16]
// ---------------------------------------------------------------------------
__global__ void prep_frags(const float* __restrict__ W1, const float* __restrict__ W2,
                           const float* __restrict__ W3, unsigned short* __restrict__ wsb) {
    int e = blockIdx.x * 256 + threadIdx.x;       // 0 .. 56*512-1
    if (e >= 56 * 512) return;
    int f = e >> 9, idx = e & 511;
    int lane = idx >> 3, j = idx & 7;
    int row = lane & 15, g = lane >> 4;
    int k = g * 8 + j;                            // 0..31 (L1 only)
    int u = f / 14, t = f % 14;
    float val;
    if (t < 4) {
        int h = 16 * t + row;
        const float* w = W1 + u * 3072;           // (48,64) row-major
        val = (k < 16) ? (w[k * 64 + h] - w[(32 + k) * 64 + h])
                       : (w[k * 64 + h] + w[(k + 16) * 64 + h]);
    } else if (t < 12) {
        int c = (t - 4) >> 1, kf = (t - 4) & 1;
        int hrow = 32 * kf + 16 * (j >> 2) + 4 * g + (j & 3);   // pi(g,j)
        val = W2[u * 4096 + hrow * 64 + 16 * c + row];
    } else {
        int kf = t - 12;
        int hrow = 32 * kf + 16 * (j >> 2) + 4 * g + (j & 3);   // pi(g,j)
        val = W3[u * 1024 + hrow * 16 + row];
    }
    wsb[e] = f2bf(val);
}

// ---------------------------------------------------------------------------
// z[b,n,d] = x[b,n,31-d]*exp(logs[d]) + bias[d]; init log_det[b].
// Also writes z1 (dims 0..15) pre-packed to bf16 (MFMA-ready).
// ---------------------------------------------------------------------------
__global__ void affine_rev(const float* __restrict__ x, const float* __restrict__ logs,
                           const float* __restrict__ bias, float* __restrict__ out,
                           unsigned short* __restrict__ z1bf) {
    __shared__ float ssc[IDIM], sbi[IDIM];
    int tid = threadIdx.x;
    if (tid < IDIM) { ssc[tid] = expf(logs[tid]); sbi[tid] = bias[tid]; }
    __syncthreads();
    size_t p = (size_t)blockIdx.x * blockDim.x + tid;
    if (p < (size_t)NBATCH * NPTS) {
        const float4* xr = (const float4*)(x + p * IDIM);
        float xv[IDIM];
#pragma unroll
        for (int q = 0; q < 8; ++q) {
            float4 v = xr[q];
            xv[q * 4 + 0] = v.x; xv[q * 4 + 1] = v.y; xv[q * 4 + 2] = v.z; xv[q * 4 + 3] = v.w;
        }
        float zv[IDIM];
#pragma unroll
        for (int d = 0; d < IDIM; ++d) zv[d] = xv[31 - d] * ssc[d] + sbi[d];
        float4* zr = (float4*)(out + p * IDIM);
#pragma unroll
        for (int q = 0; q < 8; ++q) {
            float4 v;
            v.x = zv[q * 4 + 0]; v.y = zv[q * 4 + 1];
            v.z = zv[q * 4 + 2]; v.w = zv[q * 4 + 3];
            zr[q] = v;
        }
        if (z1bf) {
            union { uint4 q[2]; unsigned w[8]; } pk;
#pragma unroll
            for (int d = 0; d < 8; ++d) pk.w[d] = pk2(zv[2 * d], zv[2 * d + 1]);
            uint4* zp = (uint4*)(z1bf + p * 16);
            zp[0] = pk.q[0]; zp[1] = pk.q[1];
        }
    }
    if (blockIdx.x == 0 && tid < NBATCH) {
        float sl = 0.f;
#pragma unroll
        for (int d = 0; d < IDIM; ++d) sl += logs[d];
        out[(size_t)NBATCH * NPTS * IDIM + tid] = sl * (float)NPTS;
    }
}

// ---------------------------------------------------------------------------
// MFMA conv kernel, 2-pt ILP + feature prefetch.
// r14: k-permutation fusion — NO inter-layer LDS staging at all. Each layer's
// B-fragments are the lane's own relu-packed D values; the k-permutation is
// folded into the prepacked W2/W3 A-fragments. Builtin MFMA (hazard-safe).
// ---------------------------------------------------------------------------
__global__ __launch_bounds__(256, 3)
void knn_mfma(const int* __restrict__ knn, const unsigned short* __restrict__ wsb,
              const unsigned short* __restrict__ z1b,
              const float* __restrict__ B1, const float* __restrict__ B2,
              const float* __restrict__ B3, float* __restrict__ out) {
    __shared__ float stg[PPB * 4 * 16];                   // [pt][net][dim]
    __shared__ float ldsum[16];
    __shared__ int   sidx[PPB * KNN];                     // 256 knn indices for this block

    const int tid = threadIdx.x;
    const int u = tid >> 6, lane = tid & 63;
    const int g = lane >> 4, x = lane & 15;
    const int pbase = blockIdx.x * PPB;
    const int bb = pbase >> 13;                           // batch (PPB divides 8192)

    // --- stage knn indices (one coalesced load per thread) ---
    sidx[tid] = knn[(size_t)pbase * KNN + tid];

    // --- weight fragments (persist across the point loop) ---
    bf16x8 a1[4], a2k0[4], a2k1[4], a30, a31;
    const int fb = u * 14;
#pragma unroll
    for (int c = 0; c < 4; ++c)
        a1[c] = *(const bf16x8*)(wsb + (size_t)(fb + c) * 512 + lane * 8);
#pragma unroll
    for (int c = 0; c < 4; ++c) {
        a2k0[c] = *(const bf16x8*)(wsb + (size_t)(fb + 4 + 2 * c + 0) * 512 + lane * 8);
        a2k1[c] = *(const bf16x8*)(wsb + (size_t)(fb + 4 + 2 * c + 1) * 512 + lane * 8);
    }
    a30 = *(const bf16x8*)(wsb + (size_t)(fb + 12) * 512 + lane * 8);
    a31 = *(const bf16x8*)(wsb + (size_t)(fb + 13) * 512 + lane * 8);

    // --- biases as persistent MFMA C-operands: lane owns rows 16c+4g..+3 ---
    f32x4 b1v[4], b2v[4], b3v;
#pragma unroll
    for (int c = 0; c < 4; ++c) {
        b1v[c] = *(const f32x4*)(B1 + u * 64 + 16 * c + 4 * g);
        b2v[c] = *(const f32x4*)(B2 + u * 64 + 16 * c + 4 * g);
    }
    b3v = *(const f32x4*)(B3 + u * 16 + 4 * g);

    const unsigned offB = (unsigned)((g & 1) << 4);       // byte offset within row
    const char* z1c = (const char*)(z1b + (size_t)bb * NPTS * 16);
    const int baseRow = pbase & (NPTS - 1);               // local row of pbase

    __syncthreads();                                      // sidx visible

    // --- prologue: features for pair 0 ---
    union fu { bf16x8 v; uint4 q; unsigned w[4]; };
    uint4 pAq, pBq, nAq, nBq;
    {
        int iA0 = sidx[x], iB0 = sidx[16 + x];
        unsigned rA = (unsigned)((g < 2) ? baseRow : iA0);
        unsigned rB = (unsigned)((g < 2) ? (baseRow + 1) : iB0);
        pAq = *(const uint4*)(z1c + ((rA << 5) + offB));
        pBq = *(const uint4*)(z1c + ((rB << 5) + offB));
    }

#pragma unroll 2
    for (int pp = 0; pp < PPB / 2; ++pp) {
        // prefetch next pair's features (indices from LDS, just-in-time)
        if (pp < PPB / 2 - 1) {
            int iA1 = sidx[(2 * pp + 2) * 16 + x];
            int iB1 = sidx[(2 * pp + 3) * 16 + x];
            unsigned rA = (unsigned)((g < 2) ? (baseRow + 2 * pp + 2) : iA1);
            unsigned rB = (unsigned)((g < 2) ? (baseRow + 2 * pp + 3) : iB1);
            nAq = *(const uint4*)(z1c + ((rA << 5) + offB));
            nBq = *(const uint4*)(z1c + ((rB << 5) + offB));
        }

        // features as MFMA B-fragments (already bf16-packed)
        fu efA, efB;
        efA.q = pAq; efB.q = pBq;

        // ---- L1 (bias in C) ----
        f32x4 aA[4], aB[4];
        __builtin_amdgcn_s_setprio(1);
#pragma unroll
        for (int c = 0; c < 4; ++c)
            aA[c] = __builtin_amdgcn_mfma_f32_16x16x32_bf16(a1[c], efA.v, b1v[c], 0, 0, 0);
#pragma unroll
        for (int c = 0; c < 4; ++c)
            aB[c] = __builtin_amdgcn_mfma_f32_16x16x32_bf16(a1[c], efB.v, b1v[c], 0, 0, 0);
        __builtin_amdgcn_s_setprio(0);

        // ---- pack h1 in-lane (k-permuted; frag kf=0 <- chunks 0,1; kf=1 <- 2,3) ----
        fu h0A, h1A, h0B, h1B;
        h0A.w[0] = relu2(pk2(aA[0][0], aA[0][1])); h0A.w[1] = relu2(pk2(aA[0][2], aA[0][3]));
        h0A.w[2] = relu2(pk2(aA[1][0], aA[1][1])); h0A.w[3] = relu2(pk2(aA[1][2], aA[1][3]));
        h1A.w[0] = relu2(pk2(aA[2][0], aA[2][1])); h1A.w[1] = relu2(pk2(aA[2][2], aA[2][3]));
        h1A.w[2] = relu2(pk2(aA[3][0], aA[3][1])); h1A.w[3] = relu2(pk2(aA[3][2], aA[3][3]));
        h0B.w[0] = relu2(pk2(aB[0][0], aB[0][1])); h0B.w[1] = relu2(pk2(aB[0][2], aB[0][3]));
        h0B.w[2] = relu2(pk2(aB[1][0], aB[1][1])); h0B.w[3] = relu2(pk2(aB[1][2], aB[1][3]));
        h1B.w[0] = relu2(pk2(aB[2][0], aB[2][1])); h1B.w[1] = relu2(pk2(aB[2][2], aB[2][3]));
        h1B.w[2] = relu2(pk2(aB[3][0], aB[3][1])); h1B.w[3] = relu2(pk2(aB[3][2], aB[3][3]));

        // ---- L2 (bias in C) ----
        f32x4 cA[4], cB[4];
        __builtin_amdgcn_s_setprio(1);
#pragma unroll
        for (int c = 0; c < 4; ++c) {
            cA[c] = __builtin_amdgcn_mfma_f32_16x16x32_bf16(a2k0[c], h0A.v, b2v[c], 0, 0, 0);
            cB[c] = __builtin_amdgcn_mfma_f32_16x16x32_bf16(a2k0[c], h0B.v, b2v[c], 0, 0, 0);
        }
#pragma unroll
        for (int c = 0; c < 4; ++c) {
            cA[c] = __builtin_amdgcn_mfma_f32_16x16x32_bf16(a2k1[c], h1A.v, cA[c], 0, 0, 0);
            cB[c] = __builtin_amdgcn_mfma_f32_16x16x32_bf16(a2k1[c], h1B.v, cB[c], 0, 0, 0);
        }
        __builtin_amdgcn_s_setprio(0);

        // ---- pack h2 in-lane ----
        fu g0A, g1A, g0B, g1B;
        g0A.w[0] = relu2(pk2(cA[0][0], cA[0][1])); g0A.w[1] = relu2(pk2(cA[0][2], cA[0][3]));
        g0A.w[2] = relu2(pk2(cA[1][0], cA[1][1])); g0A.w[3] = relu2(pk2(cA[1][2], cA[1][3]));
        g1A.w[0] = relu2(pk2(cA[2][0], cA[2][1])); g1A.w[1] = relu2(pk2(cA[2][2], cA[2][3]));
        g1A.w[2] = relu2(pk2(cA[3][0], cA[3][1])); g1A.w[3] = relu2(pk2(cA[3][2], cA[3][3]));
        g0B.w[0] = relu2(pk2(cB[0][0], cB[0][1])); g0B.w[1] = relu2(pk2(cB[0][2], cB[0][3]));
        g0B.w[2] = relu2(pk2(cB[1][0], cB[1][1])); g0B.w[3] = relu2(pk2(cB[1][2], cB[1][3]));
        g1B.w[0] = relu2(pk2(cB[2][0], cB[2][1])); g1B.w[1] = relu2(pk2(cB[2][2], cB[2][3]));
        g1B.w[2] = relu2(pk2(cB[3][0], cB[3][1])); g1B.w[3] = relu2(pk2(cB[3][2], cB[3][3]));

        // ---- L3 (bias in C) ----
        f32x4 oA, oB;
        __builtin_amdgcn_s_setprio(1);
        oA = __builtin_amdgcn_mfma_f32_16x16x32_bf16(a30, g0A.v, b3v, 0, 0, 0);
        oB = __builtin_amdgcn_mfma_f32_16x16x32_bf16(a30, g0B.v, b3v, 0, 0, 0);
        oA = __builtin_amdgcn_mfma_f32_16x16x32_bf16(a31, g1A.v, oA, 0, 0, 0);
        oB = __builtin_amdgcn_mfma_f32_16x16x32_bf16(a31, g1B.v, oB, 0, 0, 0);
        __builtin_amdgcn_s_setprio(0);

        // max over neighbors: DPP row_ror butterfly (VALU-only)
        float oA0 = red_max16(oA[0]), oA1 = red_max16(oA[1]);
        float oA2 = red_max16(oA[2]), oA3 = red_max16(oA[3]);
        float oB0 = red_max16(oB[0]), oB1 = red_max16(oB[1]);
        float oB2 = red_max16(oB[2]), oB3 = red_max16(oB[3]);

        if (x == 0) {
            *(float4*)&stg[((2 * pp + 0) * 4 + u) * 16 + 4 * g] = make_float4(oA0, oA1, oA2, oA3);
            *(float4*)&stg[((2 * pp + 1) * 4 + u) * 16 + 4 * g] = make_float4(oB0, oB1, oB2, oB3);
        }

        // rotate prefetched features
        pAq = nAq; pBq = nBq;
    }
    __syncthreads();

    // --- epilogue: z2 update + log_det (one atomic per block) ---
    {
        const int pu = u * 4 + g;                  // 0..15
        const int prow = pbase + pu;
        const size_t zoff = (size_t)prow * IDIM + 16 + x;
        float z2v = out[zoff];
        float s1 = stg[(pu * 4 + 0) * 16 + x];
        float t1 = stg[(pu * 4 + 1) * 16 + x];
        float s2 = stg[(pu * 4 + 2) * 16 + x];
        float t2 = stg[(pu * 4 + 3) * 16 + x];
        float sc1 = CLAMPV * TWO_OVER_PI * atanf(s1 * (1.0f / CLAMPV));
        float sc2 = CLAMPV * TWO_OVER_PI * atanf(s2 * (1.0f / CLAMPV));
        z2v = z2v * expf(sc1) + t1;
        z2v = z2v * expf(sc2) + t2;
        out[zoff] = z2v;
        float ss = red_sum16(sc1 + sc2);
        if (x == 0) ldsum[pu] = ss;
    }
    __syncthreads();
    if (tid == 0) {
        float tot = 0.f;
#pragma unroll
        for (int i = 0; i < 16; ++i) tot += ldsum[i];
        atomicAdd(out + (size_t)NBATCH * NPTS * IDIM + bb, tot);
    }
}

extern "C" void kernel_launch(void* const* d_in, const int* in_sizes, int n_in,
                              void* d_out, int out_size, void* d_ws, size_t ws_size,
                              hipStream_t stream) {
    const float* x    = (const float*)d_in[0];
    const int*   knn  = (const int*)d_in[1];
    const float* logs = (const float*)d_in[2];
    const float* bias = (const float*)d_in[3];
    const float* W1   = (const float*)d_in[4];
    const float* b1   = (const float*)d_in[5];
    const float* W2   = (const float*)d_in[6];
    const float* b2   = (const float*)d_in[7];
    const float* W3   = (const float*)d_in[8];
    const float* b3   = (const float*)d_in[9];
    float* out = (float*)d_out;
    unsigned short* wsb = (unsigned short*)d_ws;   // frags: 56*512 shorts = 57344 B
    unsigned short* z1bf = wsb + 56 * 512;         // packed z1: 4 MB (ws is ample)

    hipLaunchKernelGGL(prep_frags, dim3(112), dim3(256), 0, stream, W1, W2, W3, wsb);
    hipLaunchKernelGGL(affine_rev, dim3(512), dim3(256), 0, stream, x, logs, bias, out, z1bf);
    hipLaunchKernelGGL(knn_mfma, dim3((NBATCH * NPTS) / PPB), dim3(256), 0, stream,
                       knn, wsb, z1bf, b1, b2, b3, out);
}

// Round 15
// 142.925 us; speedup vs baseline: 2.6420x; 1.2077x over previous
//
#include <hip/hip_runtime.h>
#include <math.h>

#define IDIM 32
#define KNN 16
#define NPTS 8192
#define NBATCH 16
#define PPB 16                      // points per block
#define CLAMPV 1.9f
#define TWO_OVER_PI 0.63661977236758134f

typedef __attribute__((ext_vector_type(8))) short bf16x8;   // 8 bf16 = 4 VGPR (MFMA A/B)
typedef __attribute__((ext_vector_type(4))) float f32x4;    // MFMA C/D
typedef __attribute__((ext_vector_type(2))) short s16x2;

// Compiler-friendly bf16 pack: scalar __bf16 casts fuse to v_cvt_pk_bf16_f32.
__device__ __forceinline__ unsigned pk2(float a, float b) {
    union { __bf16 h[2]; unsigned u; } r;
    r.h[0] = (__bf16)a; r.h[1] = (__bf16)b;
    return r.u;
}
__device__ __forceinline__ unsigned short f2bf(float f) {
    union { __bf16 h; unsigned short u; } r; r.h = (__bf16)f; return r.u;
}

// ReLU on a packed bf16 pair: IEEE sign-magnitude => per-half smax(x,0) == relu.
__device__ __forceinline__ unsigned relu2(unsigned p) {
    s16x2 v; __builtin_memcpy(&v, &p, 4);
    s16x2 z = {0, 0};
    s16x2 m = __builtin_elementwise_max(v, z);
    unsigned r; __builtin_memcpy(&r, &m, 4);
    return r;
}

// Raw ds_swizzle (BitMode XOR) — operates within each 32-lane half.
template<int PAT>
__device__ __forceinline__ float swzf(float v) {
    return __int_as_float(__builtin_amdgcn_ds_swizzle(__float_as_int(v), PAT));
}

// DPP row-rotate within the 16-lane row: VALU-only cross-lane (epilogue sum).
template<int CTRL>
__device__ __forceinline__ float dppf(float v) {
    return __int_as_float(__builtin_amdgcn_update_dpp(
        0, __float_as_int(v), CTRL, 0xF, 0xF, true));
}
__device__ __forceinline__ float red_sum16(float o) {
    o += dppf<0x128>(o); o += dppf<0x124>(o);
    o += dppf<0x122>(o); o += dppf<0x121>(o);
    return o;
}

// ---------------------------------------------------------------------------
// Precompute MFMA A-fragments (bf16) for all 4 networks into ws.
// A-layout: lane l holds A[row=l&15][k=(l>>4)*8+j], j=0..7; ws order
// f*512 + lane*8 + j.
//
// k-PERMUTATION FUSION: pi(g,j) = 32*kf + 16*(j>>2) + 4g + (j&3) makes layer
// L's B-fragment exactly the lane's relu-packed D from layer L-1; folded into
// W2/W3 fragments here (no inter-layer LDS transpose in the conv kernel).
// The L3 frags (fb+12/13) serve as the B-operand of a transposed L3 MFMA
// (A = packed h2, rows = neighbors) — same bytes, lane&15 = output dim.
// Frag table per net u (fb = u*14):
//   fb+c        (c=0..3)        : L1  A[row][k] = W1f[k][16c+row]   (k as-is)
//   fb+4+2c+kf  (c=0..3,kf=0..1): L2  A[row][8g+j] = W2[pi(g,j)][16c+row]
//   fb+12+kf    (kf=0..1)       : L3  B[8g+j][col] = W3[pi(g,j)][col]
// W1f rows: k<16 -> WA[k]=W1[k]-W1[32+k]; k>=16 -> WB[k-16]=W1[k]+W1[k+16]
// ---------------------------------------------------------------------------
__global__ void prep_frags(const float* __restrict__ W1, const float* __restrict__ W2,
                           const float* __restrict__ W3, unsigned short* __restrict__ wsb) {
    int e = blockIdx.x * 256 + threadIdx.x;       // 0 .. 56*512-1
    if (e >= 56 * 512) return;
    int f = e >> 9, idx = e & 511;
    int lane = idx >> 3, j = idx & 7;
    int row = lane & 15, g = lane >> 4;
    int k = g * 8 + j;                            // 0..31 (L1 only)
    int u = f / 14, t = f % 14;
    float val;
    if (t < 4) {
        int h = 16 * t + row;
        const float* w = W1 + u * 3072;           // (48,64) row-major
        val = (k < 16) ? (w[k * 64 + h] - w[(32 + k) * 64 + h])
                       : (w[k * 64 + h] + w[(k + 16) * 64 + h]);
    } else if (t < 12) {
        int c = (t - 4) >> 1, kf = (t - 4) & 1;
        int hrow = 32 * kf + 16 * (j >> 2) + 4 * g + (j & 3);   // pi(g,j)
        val = W2[u * 4096 + hrow * 64 + 16 * c + row];
    } else {
        int kf = t - 12;
        int hrow = 32 * kf + 16 * (j >> 2) + 4 * g + (j & 3);   // pi(g,j)
        val = W3[u * 1024 + hrow * 16 + row];     // row = output dim (B-col)
    }
    wsb[e] = f2bf(val);
}

// ---------------------------------------------------------------------------
// z[b,n,d] = x[b,n,31-d]*exp(logs[d]) + bias[d]; init log_det[b].
// Also writes z1 (dims 0..15) pre-packed to bf16 (MFMA-ready).
// ---------------------------------------------------------------------------
__global__ void affine_rev(const float* __restrict__ x, const float* __restrict__ logs,
                           const float* __restrict__ bias, float* __restrict__ out,
                           unsigned short* __restrict__ z1bf) {
    __shared__ float ssc[IDIM], sbi[IDIM];
    int tid = threadIdx.x;
    if (tid < IDIM) { ssc[tid] = expf(logs[tid]); sbi[tid] = bias[tid]; }
    __syncthreads();
    size_t p = (size_t)blockIdx.x * blockDim.x + tid;
    if (p < (size_t)NBATCH * NPTS) {
        const float4* xr = (const float4*)(x + p * IDIM);
        float xv[IDIM];
#pragma unroll
        for (int q = 0; q < 8; ++q) {
            float4 v = xr[q];
            xv[q * 4 + 0] = v.x; xv[q * 4 + 1] = v.y; xv[q * 4 + 2] = v.z; xv[q * 4 + 3] = v.w;
        }
        float zv[IDIM];
#pragma unroll
        for (int d = 0; d < IDIM; ++d) zv[d] = xv[31 - d] * ssc[d] + sbi[d];
        float4* zr = (float4*)(out + p * IDIM);
#pragma unroll
        for (int q = 0; q < 8; ++q) {
            float4 v;
            v.x = zv[q * 4 + 0]; v.y = zv[q * 4 + 1];
            v.z = zv[q * 4 + 2]; v.w = zv[q * 4 + 3];
            zr[q] = v;
        }
        if (z1bf) {
            union { uint4 q[2]; unsigned w[8]; } pk;
#pragma unroll
            for (int d = 0; d < 8; ++d) pk.w[d] = pk2(zv[2 * d], zv[2 * d + 1]);
            uint4* zp = (uint4*)(z1bf + p * 16);
            zp[0] = pk.q[0]; zp[1] = pk.q[1];
        }
    }
    if (blockIdx.x == 0 && tid < NBATCH) {
        float sl = 0.f;
#pragma unroll
        for (int d = 0; d < IDIM; ++d) sl += logs[d];
        out[(size_t)NBATCH * NPTS * IDIM + tid] = sl * (float)NPTS;
    }
}

// ---------------------------------------------------------------------------
// MFMA conv kernel, 2-pt ILP + feature prefetch, zero inter-layer LDS.
// r15: L3 transposed (A = packed h2 with rows=neighbors, B = W3 frags) so the
// neighbor-max is 3 in-lane fmax + 1 xor16 swizzle + epilogue merge, instead
// of a 4-deep x 8-value DPP butterfly (saves ~54 VALU ops/pair-iter — we are
// issue-bound at ~550 issue-cycles/pair/wave).
// ---------------------------------------------------------------------------
__global__ __launch_bounds__(256, 3)
void knn_mfma(const int* __restrict__ knn, const unsigned short* __restrict__ wsb,
              const unsigned short* __restrict__ z1b,
              const float* __restrict__ B1, const float* __restrict__ B2,
              const float* __restrict__ B3, float* __restrict__ out) {
    __shared__ float stg[PPB * 4 * 2 * 16];               // [pt][net][half][dim]
    __shared__ float ldsum[16];
    __shared__ int   sidx[PPB * KNN];                     // 256 knn indices for this block

    const int tid = threadIdx.x;
    const int u = tid >> 6, lane = tid & 63;
    const int g = lane >> 4, x = lane & 15;
    const int pbase = blockIdx.x * PPB;
    const int bb = pbase >> 13;                           // batch (PPB divides 8192)

    // --- stage knn indices (one coalesced load per thread) ---
    sidx[tid] = knn[(size_t)pbase * KNN + tid];

    // --- weight fragments (persist across the point loop) ---
    bf16x8 a1[4], a2k0[4], a2k1[4], a30, a31;
    const int fb = u * 14;
#pragma unroll
    for (int c = 0; c < 4; ++c)
        a1[c] = *(const bf16x8*)(wsb + (size_t)(fb + c) * 512 + lane * 8);
#pragma unroll
    for (int c = 0; c < 4; ++c) {
        a2k0[c] = *(const bf16x8*)(wsb + (size_t)(fb + 4 + 2 * c + 0) * 512 + lane * 8);
        a2k1[c] = *(const bf16x8*)(wsb + (size_t)(fb + 4 + 2 * c + 1) * 512 + lane * 8);
    }
    a30 = *(const bf16x8*)(wsb + (size_t)(fb + 12) * 512 + lane * 8);
    a31 = *(const bf16x8*)(wsb + (size_t)(fb + 13) * 512 + lane * 8);

    // --- biases as persistent MFMA C-operands ---
    f32x4 b1v[4], b2v[4];
#pragma unroll
    for (int c = 0; c < 4; ++c) {
        b1v[c] = *(const f32x4*)(B1 + u * 64 + 16 * c + 4 * g);
        b2v[c] = *(const f32x4*)(B2 + u * 64 + 16 * c + 4 * g);
    }
    // L3 transposed: C[row=neighbor][col=dim] = b3[dim=x] -> per-lane splat
    const float b3x = B3[u * 16 + x];
    const f32x4 b3s = {b3x, b3x, b3x, b3x};

    const unsigned offB = (unsigned)((g & 1) << 4);       // byte offset within row
    const char* z1c = (const char*)(z1b + (size_t)bb * NPTS * 16);
    const int baseRow = pbase & (NPTS - 1);               // local row of pbase

    __syncthreads();                                      // sidx visible

    // --- prologue: features for pair 0 ---
    union fu { bf16x8 v; uint4 q; unsigned w[4]; };
    uint4 pAq, pBq, nAq, nBq;
    {
        int iA0 = sidx[x], iB0 = sidx[16 + x];
        unsigned rA = (unsigned)((g < 2) ? baseRow : iA0);
        unsigned rB = (unsigned)((g < 2) ? (baseRow + 1) : iB0);
        pAq = *(const uint4*)(z1c + ((rA << 5) + offB));
        pBq = *(const uint4*)(z1c + ((rB << 5) + offB));
    }

#pragma unroll 2
    for (int pp = 0; pp < PPB / 2; ++pp) {
        // prefetch next pair's features (indices from LDS, just-in-time)
        if (pp < PPB / 2 - 1) {
            int iA1 = sidx[(2 * pp + 2) * 16 + x];
            int iB1 = sidx[(2 * pp + 3) * 16 + x];
            unsigned rA = (unsigned)((g < 2) ? (baseRow + 2 * pp + 2) : iA1);
            unsigned rB = (unsigned)((g < 2) ? (baseRow + 2 * pp + 3) : iB1);
            nAq = *(const uint4*)(z1c + ((rA << 5) + offB));
            nBq = *(const uint4*)(z1c + ((rB << 5) + offB));
        }

        // features as MFMA B-fragments (already bf16-packed)
        fu efA, efB;
        efA.q = pAq; efB.q = pBq;

        // ---- L1 (bias in C) ----
        f32x4 aA[4], aB[4];
        __builtin_amdgcn_s_setprio(1);
#pragma unroll
        for (int c = 0; c < 4; ++c)
            aA[c] = __builtin_amdgcn_mfma_f32_16x16x32_bf16(a1[c], efA.v, b1v[c], 0, 0, 0);
#pragma unroll
        for (int c = 0; c < 4; ++c)
            aB[c] = __builtin_amdgcn_mfma_f32_16x16x32_bf16(a1[c], efB.v, b1v[c], 0, 0, 0);
        __builtin_amdgcn_s_setprio(0);

        // ---- pack h1 in-lane (k-permuted; frag kf=0 <- chunks 0,1; kf=1 <- 2,3) ----
        fu h0A, h1A, h0B, h1B;
        h0A.w[0] = relu2(pk2(aA[0][0], aA[0][1])); h0A.w[1] = relu2(pk2(aA[0][2], aA[0][3]));
        h0A.w[2] = relu2(pk2(aA[1][0], aA[1][1])); h0A.w[3] = relu2(pk2(aA[1][2], aA[1][3]));
        h1A.w[0] = relu2(pk2(aA[2][0], aA[2][1])); h1A.w[1] = relu2(pk2(aA[2][2], aA[2][3]));
        h1A.w[2] = relu2(pk2(aA[3][0], aA[3][1])); h1A.w[3] = relu2(pk2(aA[3][2], aA[3][3]));
        h0B.w[0] = relu2(pk2(aB[0][0], aB[0][1])); h0B.w[1] = relu2(pk2(aB[0][2], aB[0][3]));
        h0B.w[2] = relu2(pk2(aB[1][0], aB[1][1])); h0B.w[3] = relu2(pk2(aB[1][2], aB[1][3]));
        h1B.w[0] = relu2(pk2(aB[2][0], aB[2][1])); h1B.w[1] = relu2(pk2(aB[2][2], aB[2][3]));
        h1B.w[2] = relu2(pk2(aB[3][0], aB[3][1])); h1B.w[3] = relu2(pk2(aB[3][2], aB[3][3]));

        // ---- L2 (bias in C) ----
        f32x4 cA[4], cB[4];
        __builtin_amdgcn_s_setprio(1);
#pragma unroll
        for (int c = 0; c < 4; ++c) {
            cA[c] = __builtin_amdgcn_mfma_f32_16x16x32_bf16(a2k0[c], h0A.v, b2v[c], 0, 0, 0);
            cB[c] = __builtin_amdgcn_mfma_f32_16x16x32_bf16(a2k0[c], h0B.v, b2v[c], 0, 0, 0);
        }
#pragma unroll
        for (int c = 0; c < 4; ++c) {
            cA[c] = __builtin_amdgcn_mfma_f32_16x16x32_bf16(a2k1[c], h1A.v, cA[c], 0, 0, 0);
            cB[c] = __builtin_amdgcn_mfma_f32_16x16x32_bf16(a2k1[c], h1B.v, cB[c], 0, 0, 0);
        }
        __builtin_amdgcn_s_setprio(0);

        // ---- pack h2 in-lane ----
        fu g0A, g1A, g0B, g1B;
        g0A.w[0] = relu2(pk2(cA[0][0], cA[0][1])); g0A.w[1] = relu2(pk2(cA[0][2], cA[0][3]));
        g0A.w[2] = relu2(pk2(cA[1][0], cA[1][1])); g0A.w[3] = relu2(pk2(cA[1][2], cA[1][3]));
        g1A.w[0] = relu2(pk2(cA[2][0], cA[2][1])); g1A.w[1] = relu2(pk2(cA[2][2], cA[2][3]));
        g1A.w[2] = relu2(pk2(cA[3][0], cA[3][1])); g1A.w[3] = relu2(pk2(cA[3][2], cA[3][3]));
        g0B.w[0] = relu2(pk2(cB[0][0], cB[0][1])); g0B.w[1] = relu2(pk2(cB[0][2], cB[0][3]));
        g0B.w[2] = relu2(pk2(cB[1][0], cB[1][1])); g0B.w[3] = relu2(pk2(cB[1][2], cB[1][3]));
        g1B.w[0] = relu2(pk2(cB[2][0], cB[2][1])); g1B.w[1] = relu2(pk2(cB[2][2], cB[2][3]));
        g1B.w[2] = relu2(pk2(cB[3][0], cB[3][1])); g1B.w[3] = relu2(pk2(cB[3][2], cB[3][3]));

        // ---- L3 TRANSPOSED: A = packed h2 (rows = neighbors), B = W3 frags ----
        // D[row=neighbor quad (lane>>4)*4+r][col=dim (lane&15)]
        f32x4 oA, oB;
        __builtin_amdgcn_s_setprio(1);
        oA = __builtin_amdgcn_mfma_f32_16x16x32_bf16(g0A.v, a30, b3s, 0, 0, 0);
        oB = __builtin_amdgcn_mfma_f32_16x16x32_bf16(g0B.v, a30, b3s, 0, 0, 0);
        oA = __builtin_amdgcn_mfma_f32_16x16x32_bf16(g1A.v, a31, oA, 0, 0, 0);
        oB = __builtin_amdgcn_mfma_f32_16x16x32_bf16(g1B.v, a31, oB, 0, 0, 0);
        __builtin_amdgcn_s_setprio(0);

        // ---- neighbor-max: 3 in-lane fmax + xor16 (g-pair merge) ----
        float mA = fmaxf(fmaxf(oA[0], oA[1]), fmaxf(oA[2], oA[3]));
        float mB = fmaxf(fmaxf(oB[0], oB[1]), fmaxf(oB[2], oB[3]));
        mA = fmaxf(mA, swzf<0x401F>(mA));   // xor 16 within each 32-lane half
        mB = fmaxf(mB, swzf<0x401F>(mB));
        if ((lane & 16) == 0) {             // g==0 (half 0: nbrs 0-7), g==2 (half 1: nbrs 8-15)
            const int h = g >> 1;
            stg[(((2 * pp + 0) * 4 + u) * 2 + h) * 16 + x] = mA;
            stg[(((2 * pp + 1) * 4 + u) * 2 + h) * 16 + x] = mB;
        }

        // rotate prefetched features
        pAq = nAq; pBq = nBq;
    }
    __syncthreads();

    // --- epilogue: z2 update + log_det (one atomic per block) ---
    {
        const int pu = u * 4 + g;                  // 0..15
        const int prow = pbase + pu;
        const size_t zoff = (size_t)prow * IDIM + 16 + x;
        float z2v = out[zoff];
        float s1 = fmaxf(stg[((pu * 4 + 0) * 2 + 0) * 16 + x], stg[((pu * 4 + 0) * 2 + 1) * 16 + x]);
        float t1 = fmaxf(stg[((pu * 4 + 1) * 2 + 0) * 16 + x], stg[((pu * 4 + 1) * 2 + 1) * 16 + x]);
        float s2 = fmaxf(stg[((pu * 4 + 2) * 2 + 0) * 16 + x], stg[((pu * 4 + 2) * 2 + 1) * 16 + x]);
        float t2 = fmaxf(stg[((pu * 4 + 3) * 2 + 0) * 16 + x], stg[((pu * 4 + 3) * 2 + 1) * 16 + x]);
        float sc1 = CLAMPV * TWO_OVER_PI * atanf(s1 * (1.0f / CLAMPV));
        float sc2 = CLAMPV * TWO_OVER_PI * atanf(s2 * (1.0f / CLAMPV));
        z2v = z2v * expf(sc1) + t1;
        z2v = z2v * expf(sc2) + t2;
        out[zoff] = z2v;
        float ss = red_sum16(sc1 + sc2);
        if (x == 0) ldsum[pu] = ss;
    }
    __syncthreads();
    if (tid == 0) {
        float tot = 0.f;
#pragma unroll
        for (int i = 0; i < 16; ++i) tot += ldsum[i];
        atomicAdd(out + (size_t)NBATCH * NPTS * IDIM + bb, tot);
    }
}

extern "C" void kernel_launch(void* const* d_in, const int* in_sizes, int n_in,
                              void* d_out, int out_size, void* d_ws, size_t ws_size,
                              hipStream_t stream) {
    const float* x    = (const float*)d_in[0];
    const int*   knn  = (const int*)d_in[1];
    const float* logs = (const float*)d_in[2];
    const float* bias = (const float*)d_in[3];
    const float* W1   = (const float*)d_in[4];
    const float* b1   = (const float*)d_in[5];
    const float* W2   = (const float*)d_in[6];
    const float* b2   = (const float*)d_in[7];
    const float* W3   = (const float*)d_in[8];
    const float* b3   = (const float*)d_in[9];
    float* out = (float*)d_out;
    unsigned short* wsb = (unsigned short*)d_ws;   // frags: 56*512 shorts = 57344 B
    unsigned short* z1bf = wsb + 56 * 512;         // packed z1: 4 MB (ws is ample)

    hipLaunchKernelGGL(prep_frags, dim3(112), dim3(256), 0, stream, W1, W2, W3, wsb);
    hipLaunchKernelGGL(affine_rev, dim3(512), dim3(256), 0, stream, x, logs, bias, out, z1bf);
    hipLaunchKernelGGL(knn_mfma, dim3((NBATCH * NPTS) / PPB), dim3(256), 0, stream,
                       knn, wsb, z1bf, b1, b2, b3, out);
}